// Round 1
// baseline (707.969 us; speedup 1.0000x reference)
//
#include <hip/hip_runtime.h>
#include <hip/hip_bf16.h>

#define N_NODES 50000
#define N_EDGES 800000
// C=128, H=2 -> h row = 256 floats

static __device__ __forceinline__ float lrelu(float v) { return v > 0.0f ? v : 0.2f * v; }

// ---------------- CSR build ----------------
__global__ __launch_bounds__(256) void degree_kernel(const int* __restrict__ ei, int* __restrict__ deg) {
    int i = blockIdx.x * 256 + threadIdx.x;
    int total = N_EDGES + N_NODES;
    if (i >= total) return;
    int d = (i < N_EDGES) ? ei[N_EDGES + i] : (i - N_EDGES);
    atomicAdd(&deg[d], 1);
}

__global__ __launch_bounds__(1024) void scan_kernel(const int* __restrict__ deg, int* __restrict__ ptr) {
    __shared__ int ps[1024];
    int t = threadIdx.x;
    const int chunk = (N_NODES + 1023) / 1024;  // 49
    int lo = t * chunk;
    int hi = lo + chunk;
    if (lo > N_NODES) lo = N_NODES;
    if (hi > N_NODES) hi = N_NODES;
    int s = 0;
    for (int i = lo; i < hi; ++i) s += deg[i];
    ps[t] = s;
    __syncthreads();
    for (int o = 1; o < 1024; o <<= 1) {
        int v = (t >= o) ? ps[t - o] : 0;
        __syncthreads();
        ps[t] += v;
        __syncthreads();
    }
    int run = ps[t] - s;  // exclusive prefix
    for (int i = lo; i < hi; ++i) { ptr[i] = run; run += deg[i]; }
    if (t == 1023) ptr[N_NODES] = ps[1023];
}

__global__ __launch_bounds__(256) void fill_kernel(const int* __restrict__ ei, const int* __restrict__ ptr,
                                                   int* __restrict__ cur, int* __restrict__ srcs) {
    int i = blockIdx.x * 256 + threadIdx.x;
    int total = N_EDGES + N_NODES;
    if (i >= total) return;
    int s, d;
    if (i < N_EDGES) { s = ei[i]; d = ei[N_EDGES + i]; }
    else { s = d = i - N_EDGES; }
    int p = atomicAdd(&cur[d], 1);
    srcs[ptr[d] + p] = s;
}

// ---------------- per-layer kernels ----------------
// h = x @ W  : (N,128) @ (128,256) -> (N,256)
// block = 256 threads, tile = 32 rows; thread = 8 rows x 4 consecutive cols
__global__ __launch_bounds__(256) void gemm_kernel(const float* __restrict__ x, const float* __restrict__ W,
                                                   float* __restrict__ h) {
    int t = threadIdx.x;
    int rg = t >> 6;          // row group 0..3
    int lane = t & 63;
    int row0 = blockIdx.x * 32 + rg * 8;
    int c4 = lane * 4;        // 0..252

    const float* xr[8];
#pragma unroll
    for (int r = 0; r < 8; ++r) {
        int rr = row0 + r;
        if (rr >= N_NODES) rr = N_NODES - 1;
        xr[r] = x + (size_t)rr * 128;
    }

    float acc[8][4];
#pragma unroll
    for (int r = 0; r < 8; ++r)
#pragma unroll
        for (int j = 0; j < 4; ++j) acc[r][j] = 0.0f;

    for (int k = 0; k < 128; k += 4) {
        float4 xv[8];
#pragma unroll
        for (int r = 0; r < 8; ++r) xv[r] = *(const float4*)(xr[r] + k);
#pragma unroll
        for (int kk = 0; kk < 4; ++kk) {
            float4 w = *(const float4*)(W + (size_t)(k + kk) * 256 + c4);
#pragma unroll
            for (int r = 0; r < 8; ++r) {
                float xs = ((const float*)&xv[r])[kk];
                acc[r][0] += xs * w.x;
                acc[r][1] += xs * w.y;
                acc[r][2] += xs * w.z;
                acc[r][3] += xs * w.w;
            }
        }
    }
#pragma unroll
    for (int r = 0; r < 8; ++r) {
        int rr = row0 + r;
        if (rr < N_NODES) {
            float4 o = make_float4(acc[r][0], acc[r][1], acc[r][2], acc[r][3]);
            *(float4*)(h + (size_t)rr * 256 + c4) = o;
        }
    }
}

// per-node attention logits: al[n] = {sum h0*as0, sum h1*as1, sum h0*ad0, sum h1*ad1}
__global__ __launch_bounds__(256) void al_kernel(const float* __restrict__ h, const float* __restrict__ as,
                                                 const float* __restrict__ ad, float* __restrict__ al) {
    int wid = (blockIdx.x * 256 + threadIdx.x) >> 6;
    int lane = threadIdx.x & 63;
    if (wid >= N_NODES) return;
    const float* hp = h + (size_t)wid * 256;
    float v0 = hp[lane], v1 = hp[64 + lane], v2 = hp[128 + lane], v3 = hp[192 + lane];
    float s0 = v0 * as[lane] + v1 * as[64 + lane];
    float s1 = v2 * as[128 + lane] + v3 * as[192 + lane];
    float d0 = v0 * ad[lane] + v1 * ad[64 + lane];
    float d1 = v2 * ad[128 + lane] + v3 * ad[192 + lane];
#pragma unroll
    for (int o = 32; o; o >>= 1) {
        s0 += __shfl_xor(s0, o);
        s1 += __shfl_xor(s1, o);
        d0 += __shfl_xor(d0, o);
        d1 += __shfl_xor(d1, o);
    }
    if (lane == 0) *(float4*)(al + (size_t)wid * 4) = make_float4(s0, s1, d0, d1);
}

// one wave per destination node: online segment softmax + weighted aggregation
__global__ __launch_bounds__(256) void agg_kernel(const float* __restrict__ h, const float* __restrict__ al,
                                                  const int* __restrict__ ptr, const int* __restrict__ srcs,
                                                  const float* __restrict__ bias, float* __restrict__ agg) {
    int n = (blockIdx.x * 256 + threadIdx.x) >> 6;
    int lane = threadIdx.x & 63;
    if (n >= N_NODES) return;
    int b = ptr[n], e = ptr[n + 1];
    float ald0 = al[(size_t)n * 4 + 2], ald1 = al[(size_t)n * 4 + 3];

    // pass 1: per-head max (lane-parallel + shuffle reduce)
    float m0 = -1e30f, m1 = -1e30f;
    for (int i = b + lane; i < e; i += 64) {
        int s = srcs[i];
        float e0 = lrelu(al[(size_t)s * 4 + 0] + ald0);
        float e1 = lrelu(al[(size_t)s * 4 + 1] + ald1);
        m0 = fmaxf(m0, e0);
        m1 = fmaxf(m1, e1);
    }
#pragma unroll
    for (int o = 32; o; o >>= 1) {
        m0 = fmaxf(m0, __shfl_xor(m0, o));
        m1 = fmaxf(m1, __shfl_xor(m1, o));
    }

    // pass 2: accumulate exp-weighted h[src] and denominators
    float a0 = 0.f, a1 = 0.f, a2 = 0.f, a3 = 0.f, d0 = 0.f, d1 = 0.f;
    for (int i = b; i < e; ++i) {
        int s = srcs[i];
        float e0 = lrelu(al[(size_t)s * 4 + 0] + ald0);
        float e1 = lrelu(al[(size_t)s * 4 + 1] + ald1);
        float x0 = __expf(e0 - m0);
        float x1 = __expf(e1 - m1);
        d0 += x0;
        d1 += x1;
        const float* hp = h + (size_t)s * 256;
        a0 += x0 * hp[lane];
        a1 += x0 * hp[64 + lane];
        a2 += x1 * hp[128 + lane];
        a3 += x1 * hp[192 + lane];
    }
    float r0 = 0.5f * (a0 / d0 + a2 / d1) + bias[lane];
    float r1 = 0.5f * (a1 / d0 + a3 / d1) + bias[64 + lane];
    agg[(size_t)n * 128 + lane] = r0;
    agg[(size_t)n * 128 + 64 + lane] = r1;
}

// per-channel sum and sumsq
__global__ __launch_bounds__(256) void stats_kernel(const float* __restrict__ agg, float* __restrict__ stats) {
    __shared__ float ls[256], lq[256];
    int t = threadIdx.x;
    int c = t & 127, half = t >> 7;
    float s = 0.f, q = 0.f;
    for (int r = blockIdx.x * 2 + half; r < N_NODES; r += gridDim.x * 2) {
        float v = agg[(size_t)r * 128 + c];
        s += v;
        q += v * v;
    }
    ls[t] = s;
    lq[t] = q;
    __syncthreads();
    if (half == 0) {
        atomicAdd(&stats[c], s + ls[128 + c]);
        atomicAdd(&stats[128 + c], q + lq[128 + c]);
    }
}

// BN + ELU + residual
__global__ __launch_bounds__(256) void final_kernel(const float* __restrict__ agg, const float* __restrict__ res,
                                                    const float* __restrict__ gamma, const float* __restrict__ beta,
                                                    const float* __restrict__ stats, float* __restrict__ out) {
    const float invn = 1.0f / (float)N_NODES;
    int total = N_NODES * 32;  // float4 count
    for (int idx = blockIdx.x * 256 + threadIdx.x; idx < total; idx += gridDim.x * 256) {
        int c4 = (idx & 31) * 4;
        float4 v = ((const float4*)agg)[idx];
        float4 r = ((const float4*)res)[idx];
        const float* vp = (const float*)&v;
        const float* rp = (const float*)&r;
        float4 ov;
        float* op = (float*)&ov;
#pragma unroll
        for (int j = 0; j < 4; ++j) {
            int c = c4 + j;
            float mean = stats[c] * invn;
            float var = stats[128 + c] * invn - mean * mean;
            float is = rsqrtf(var + 1e-5f) * gamma[c];
            float val = (vp[j] - mean) * is + beta[c];
            val = val > 0.f ? val : (__expf(val) - 1.0f);
            op[j] = val + rp[j];
        }
        ((float4*)out)[idx] = ov;
    }
}

extern "C" void kernel_launch(void* const* d_in, const int* in_sizes, int n_in,
                              void* d_out, int out_size, void* d_ws, size_t ws_size,
                              hipStream_t stream) {
    const float* x0   = (const float*)d_in[0];
    const int* ei     = (const int*)d_in[1];
    const float* W    = (const float*)d_in[2];
    const float* asrc = (const float*)d_in[3];
    const float* adst = (const float*)d_in[4];
    const float* bias = (const float*)d_in[5];
    const float* gam  = (const float*)d_in[6];
    const float* bet  = (const float*)d_in[7];
    float* out = (float*)d_out;

    char* ws = (char*)d_ws;
    size_t off = 0;
    auto alloc = [&](size_t bytes) -> void* {
        void* p = ws + off;
        off += (bytes + 255) & ~(size_t)255;
        return p;
    };
    int* deg    = (int*)alloc((size_t)N_NODES * 4);
    int* cur    = (int*)alloc((size_t)N_NODES * 4);
    int* ptr    = (int*)alloc((size_t)(N_NODES + 1) * 4);
    int* srcs   = (int*)alloc((size_t)(N_EDGES + N_NODES) * 4);
    float* h    = (float*)alloc((size_t)N_NODES * 256 * 4);
    float* al   = (float*)alloc((size_t)N_NODES * 4 * 4);
    float* agg  = (float*)alloc((size_t)N_NODES * 128 * 4);
    float* x1   = (float*)alloc((size_t)N_NODES * 128 * 4);
    float* stats = (float*)alloc(512 * 4);

    hipMemsetAsync(deg, 0, (size_t)N_NODES * 4, stream);
    hipMemsetAsync(cur, 0, (size_t)N_NODES * 4, stream);
    hipMemsetAsync(stats, 0, 512 * 4, stream);

    int tot = N_EDGES + N_NODES;
    degree_kernel<<<(tot + 255) / 256, 256, 0, stream>>>(ei, deg);
    scan_kernel<<<1, 1024, 0, stream>>>(deg, ptr);
    fill_kernel<<<(tot + 255) / 256, 256, 0, stream>>>(ei, ptr, cur, srcs);

    for (int l = 0; l < 2; ++l) {
        const float* xin = l ? (const float*)x1 : x0;
        float* xout = l ? out : x1;
        gemm_kernel<<<(N_NODES + 31) / 32, 256, 0, stream>>>(xin, W + (size_t)l * 128 * 256, h);
        al_kernel<<<(N_NODES + 3) / 4, 256, 0, stream>>>(h, asrc + l * 256, adst + l * 256, al);
        agg_kernel<<<(N_NODES + 3) / 4, 256, 0, stream>>>(h, al, ptr, srcs, bias + l * 128, agg);
        stats_kernel<<<256, 256, 0, stream>>>(agg, stats + l * 256);
        final_kernel<<<2048, 256, 0, stream>>>(agg, xin, gam + l * 128, bet + l * 128, stats + l * 256, xout);
    }
}

// Round 2
// 621.753 us; speedup vs baseline: 1.1387x; 1.1387x over previous
//
#include <hip/hip_runtime.h>
#include <hip/hip_bf16.h>

#define N_NODES 50000
#define N_EDGES 800000
// C=128, H=2 -> h row = 256 cols

static __device__ __forceinline__ float lrelu(float v) { return v > 0.0f ? v : 0.2f * v; }

static __device__ __forceinline__ unsigned short f2bf(float f) {
    unsigned int u = __float_as_uint(f);
    unsigned int r = (u + 0x7FFF + ((u >> 16) & 1)) >> 16;  // RNE
    return (unsigned short)r;
}
static __device__ __forceinline__ float bf2f(unsigned short u) {
    return __uint_as_float(((unsigned int)u) << 16);
}

// ---------------- CSR build ----------------
__global__ __launch_bounds__(256) void degree_kernel(const int* __restrict__ ei, int* __restrict__ deg) {
    int i = blockIdx.x * 256 + threadIdx.x;
    int total = N_EDGES + N_NODES;
    if (i >= total) return;
    int d = (i < N_EDGES) ? ei[N_EDGES + i] : (i - N_EDGES);
    atomicAdd(&deg[d], 1);
}

__global__ __launch_bounds__(1024) void scan_kernel(const int* __restrict__ deg, int* __restrict__ ptr) {
    __shared__ int ps[1024];
    int t = threadIdx.x;
    const int chunk = (N_NODES + 1023) / 1024;  // 49
    int lo = t * chunk;
    int hi = lo + chunk;
    if (lo > N_NODES) lo = N_NODES;
    if (hi > N_NODES) hi = N_NODES;
    int s = 0;
    for (int i = lo; i < hi; ++i) s += deg[i];
    ps[t] = s;
    __syncthreads();
    for (int o = 1; o < 1024; o <<= 1) {
        int v = (t >= o) ? ps[t - o] : 0;
        __syncthreads();
        ps[t] += v;
        __syncthreads();
    }
    int run = ps[t] - s;  // exclusive prefix
    for (int i = lo; i < hi; ++i) { ptr[i] = run; run += deg[i]; }
    if (t == 1023) ptr[N_NODES] = ps[1023];
}

__global__ __launch_bounds__(256) void fill_kernel(const int* __restrict__ ei, const int* __restrict__ ptr,
                                                   int* __restrict__ cur, int* __restrict__ srcs) {
    int i = blockIdx.x * 256 + threadIdx.x;
    int total = N_EDGES + N_NODES;
    if (i >= total) return;
    int s, d;
    if (i < N_EDGES) { s = ei[i]; d = ei[N_EDGES + i]; }
    else { s = d = i - N_EDGES; }
    int p = atomicAdd(&cur[d], 1);
    srcs[ptr[d] + p] = s;
}

// ---------------- per-layer kernels ----------------
// h = x @ W : (N,128)@(128,256) -> bf16 h (N,256), plus fused attention logits
// block = 256 threads, tile = 32 rows; wave owns 8 rows, lane covers 4 consecutive cols
__global__ __launch_bounds__(256) void gemm_kernel(const float* __restrict__ x, const float* __restrict__ W,
                                                   const float* __restrict__ as_, const float* __restrict__ ad_,
                                                   unsigned short* __restrict__ hb,
                                                   float* __restrict__ als, float* __restrict__ ald) {
    int t = threadIdx.x;
    int rg = t >> 6;          // row group 0..3 == wave id
    int lane = t & 63;
    int row0 = blockIdx.x * 32 + rg * 8;
    int c4 = lane * 4;        // 0..252

    const float* xr[8];
#pragma unroll
    for (int r = 0; r < 8; ++r) {
        int rr = row0 + r;
        if (rr >= N_NODES) rr = N_NODES - 1;
        xr[r] = x + (size_t)rr * 128;
    }

    float acc[8][4];
#pragma unroll
    for (int r = 0; r < 8; ++r)
#pragma unroll
        for (int j = 0; j < 4; ++j) acc[r][j] = 0.0f;

    for (int k = 0; k < 128; k += 4) {
        float4 xv[8];
#pragma unroll
        for (int r = 0; r < 8; ++r) xv[r] = *(const float4*)(xr[r] + k);
#pragma unroll
        for (int kk = 0; kk < 4; ++kk) {
            float4 w = *(const float4*)(W + (size_t)(k + kk) * 256 + c4);
#pragma unroll
            for (int r = 0; r < 8; ++r) {
                float xs = ((const float*)&xv[r])[kk];
                acc[r][0] += xs * w.x;
                acc[r][1] += xs * w.y;
                acc[r][2] += xs * w.z;
                acc[r][3] += xs * w.w;
            }
        }
    }

    float4 asv = *(const float4*)(as_ + c4);
    float4 adv = *(const float4*)(ad_ + c4);
#pragma unroll
    for (int r = 0; r < 8; ++r) {
        int rr = row0 + r;
        float ps = acc[r][0] * asv.x + acc[r][1] * asv.y + acc[r][2] * asv.z + acc[r][3] * asv.w;
        float pd = acc[r][0] * adv.x + acc[r][1] * adv.y + acc[r][2] * adv.z + acc[r][3] * adv.w;
#pragma unroll
        for (int o = 16; o; o >>= 1) {  // reduce within each 32-lane half (one head each)
            ps += __shfl_xor(ps, o);
            pd += __shfl_xor(pd, o);
        }
        if (rr < N_NODES) {
            if (lane == 0 || lane == 32) {
                int head = lane >> 5;
                als[(size_t)rr * 2 + head] = ps;
                ald[(size_t)rr * 2 + head] = pd;
            }
            ushort4 o4;
            o4.x = f2bf(acc[r][0]);
            o4.y = f2bf(acc[r][1]);
            o4.z = f2bf(acc[r][2]);
            o4.w = f2bf(acc[r][3]);
            *(ushort4*)(hb + (size_t)rr * 256 + c4) = o4;
        }
    }
}

// one wave per destination node: single-pass segment softmax (no max-sub) + aggregation
// lane covers 4 consecutive bf16 cols; lanes 0-31 = head0, 32-63 = head1
__global__ __launch_bounds__(256) void agg_kernel(const unsigned short* __restrict__ hb,
                                                  const float2* __restrict__ als, const float2* __restrict__ ald,
                                                  const int* __restrict__ ptr, const int* __restrict__ srcs,
                                                  const float* __restrict__ bias, float* __restrict__ agg) {
    int n = (blockIdx.x * 256 + threadIdx.x) >> 6;
    int lane = threadIdx.x & 63;
    if (n >= N_NODES) return;
    int b = ptr[n], e = ptr[n + 1];
    float2 ad = ald[n];
    bool head1 = lane >= 32;

    float a0 = 0.f, a1 = 0.f, a2 = 0.f, a3 = 0.f, d0 = 0.f, d1 = 0.f;
    for (int i = b; i < e; ++i) {
        int s = srcs[i];
        float2 as2 = als[s];                       // broadcast (same addr all lanes)
        float x0 = __expf(lrelu(as2.x + ad.x));
        float x1 = __expf(lrelu(as2.y + ad.y));
        d0 += x0;
        d1 += x1;
        float w = head1 ? x1 : x0;
        ushort4 hv = *(const ushort4*)(hb + (size_t)s * 256 + lane * 4);  // 8B/lane, full row per wave
        a0 += w * bf2f(hv.x);
        a1 += w * bf2f(hv.y);
        a2 += w * bf2f(hv.z);
        a3 += w * bf2f(hv.w);
    }
    float rinv = 1.0f / (head1 ? d1 : d0);
    float r0 = a0 * rinv, r1 = a1 * rinv, r2 = a2 * rinv, r3 = a3 * rinv;
    float o0 = __shfl_xor(r0, 32);
    float o1 = __shfl_xor(r1, 32);
    float o2 = __shfl_xor(r2, 32);
    float o3 = __shfl_xor(r3, 32);
    if (!head1) {
        int c = lane * 4;
        float4 bv = *(const float4*)(bias + c);
        float4 res;
        res.x = 0.5f * (r0 + o0) + bv.x;
        res.y = 0.5f * (r1 + o1) + bv.y;
        res.z = 0.5f * (r2 + o2) + bv.z;
        res.w = 0.5f * (r3 + o3) + bv.w;
        *(float4*)(agg + (size_t)n * 128 + c) = res;
    }
}

// per-channel sum and sumsq
__global__ __launch_bounds__(256) void stats_kernel(const float* __restrict__ agg, float* __restrict__ stats) {
    __shared__ float ls[256], lq[256];
    int t = threadIdx.x;
    int c = t & 127, half = t >> 7;
    float s = 0.f, q = 0.f;
    for (int r = blockIdx.x * 2 + half; r < N_NODES; r += gridDim.x * 2) {
        float v = agg[(size_t)r * 128 + c];
        s += v;
        q += v * v;
    }
    ls[t] = s;
    lq[t] = q;
    __syncthreads();
    if (half == 0) {
        atomicAdd(&stats[c], s + ls[128 + c]);
        atomicAdd(&stats[128 + c], q + lq[128 + c]);
    }
}

// BN + ELU + residual
__global__ __launch_bounds__(256) void final_kernel(const float* __restrict__ agg, const float* __restrict__ res,
                                                    const float* __restrict__ gamma, const float* __restrict__ beta,
                                                    const float* __restrict__ stats, float* __restrict__ out) {
    const float invn = 1.0f / (float)N_NODES;
    int total = N_NODES * 32;  // float4 count
    for (int idx = blockIdx.x * 256 + threadIdx.x; idx < total; idx += gridDim.x * 256) {
        int c4 = (idx & 31) * 4;
        float4 v = ((const float4*)agg)[idx];
        float4 r = ((const float4*)res)[idx];
        const float* vp = (const float*)&v;
        const float* rp = (const float*)&r;
        float4 ov;
        float* op = (float*)&ov;
#pragma unroll
        for (int j = 0; j < 4; ++j) {
            int c = c4 + j;
            float mean = stats[c] * invn;
            float var = stats[128 + c] * invn - mean * mean;
            float is = rsqrtf(var + 1e-5f) * gamma[c];
            float val = (vp[j] - mean) * is + beta[c];
            val = val > 0.f ? val : (__expf(val) - 1.0f);
            op[j] = val + rp[j];
        }
        ((float4*)out)[idx] = ov;
    }
}

extern "C" void kernel_launch(void* const* d_in, const int* in_sizes, int n_in,
                              void* d_out, int out_size, void* d_ws, size_t ws_size,
                              hipStream_t stream) {
    const float* x0   = (const float*)d_in[0];
    const int* ei     = (const int*)d_in[1];
    const float* W    = (const float*)d_in[2];
    const float* asrc = (const float*)d_in[3];
    const float* adst = (const float*)d_in[4];
    const float* bias = (const float*)d_in[5];
    const float* gam  = (const float*)d_in[6];
    const float* bet  = (const float*)d_in[7];
    float* out = (float*)d_out;

    char* ws = (char*)d_ws;
    size_t off = 0;
    auto alloc = [&](size_t bytes) -> void* {
        void* p = ws + off;
        off += (bytes + 255) & ~(size_t)255;
        return p;
    };
    int* deg    = (int*)alloc((size_t)N_NODES * 4);
    int* cur    = (int*)alloc((size_t)N_NODES * 4);
    int* ptr    = (int*)alloc((size_t)(N_NODES + 1) * 4);
    int* srcs   = (int*)alloc((size_t)(N_EDGES + N_NODES) * 4);
    unsigned short* hb = (unsigned short*)alloc((size_t)N_NODES * 256 * 2);  // bf16 h
    float* als  = (float*)alloc((size_t)N_NODES * 2 * 4);
    float* ald  = (float*)alloc((size_t)N_NODES * 2 * 4);
    float* agg  = (float*)alloc((size_t)N_NODES * 128 * 4);
    float* x1   = (float*)alloc((size_t)N_NODES * 128 * 4);
    float* stats = (float*)alloc(512 * 4);

    hipMemsetAsync(deg, 0, (size_t)N_NODES * 4, stream);
    hipMemsetAsync(cur, 0, (size_t)N_NODES * 4, stream);
    hipMemsetAsync(stats, 0, 512 * 4, stream);

    int tot = N_EDGES + N_NODES;
    degree_kernel<<<(tot + 255) / 256, 256, 0, stream>>>(ei, deg);
    scan_kernel<<<1, 1024, 0, stream>>>(deg, ptr);
    fill_kernel<<<(tot + 255) / 256, 256, 0, stream>>>(ei, ptr, cur, srcs);

    for (int l = 0; l < 2; ++l) {
        const float* xin = l ? (const float*)x1 : x0;
        float* xout = l ? out : x1;
        gemm_kernel<<<(N_NODES + 31) / 32, 256, 0, stream>>>(
            xin, W + (size_t)l * 128 * 256, asrc + l * 256, adst + l * 256, hb, als, ald);
        agg_kernel<<<(N_NODES + 3) / 4, 256, 0, stream>>>(
            hb, (const float2*)als, (const float2*)ald, ptr, srcs, bias + l * 128, agg);
        stats_kernel<<<256, 256, 0, stream>>>(agg, stats + l * 256);
        final_kernel<<<2048, 256, 0, stream>>>(agg, xin, gam + l * 128, bet + l * 128, stats + l * 256, xout);
    }
}

// Round 3
// 546.110 us; speedup vs baseline: 1.2964x; 1.1385x over previous
//
#include <hip/hip_runtime.h>
#include <hip/hip_bf16.h>

#define N_NODES 50000
#define N_EDGES 800000
// C=128, H=2 -> h row = 256 cols

typedef unsigned short us8 __attribute__((ext_vector_type(8)));

static __device__ __forceinline__ float lrelu(float v) { return v > 0.0f ? v : 0.2f * v; }

static __device__ __forceinline__ unsigned short f2bf(float f) {
    unsigned int u = __float_as_uint(f);
    unsigned int r = (u + 0x7FFF + ((u >> 16) & 1)) >> 16;  // RNE
    return (unsigned short)r;
}
static __device__ __forceinline__ float bf2f(unsigned short u) {
    return __uint_as_float(((unsigned int)u) << 16);
}

// ---------------- CSR build ----------------
__global__ __launch_bounds__(256) void degree_kernel(const int* __restrict__ ei, int* __restrict__ deg) {
    int i = blockIdx.x * 256 + threadIdx.x;
    int total = N_EDGES + N_NODES;
    if (i >= total) return;
    int d = (i < N_EDGES) ? ei[N_EDGES + i] : (i - N_EDGES);
    atomicAdd(&deg[d], 1);
}

__global__ __launch_bounds__(1024) void scan_kernel(const int* __restrict__ deg, int* __restrict__ ptr) {
    __shared__ int ps[1024];
    int t = threadIdx.x;
    const int chunk = (N_NODES + 1023) / 1024;  // 49
    int lo = t * chunk;
    int hi = lo + chunk;
    if (lo > N_NODES) lo = N_NODES;
    if (hi > N_NODES) hi = N_NODES;
    int s = 0;
    for (int i = lo; i < hi; ++i) s += deg[i];
    ps[t] = s;
    __syncthreads();
    for (int o = 1; o < 1024; o <<= 1) {
        int v = (t >= o) ? ps[t - o] : 0;
        __syncthreads();
        ps[t] += v;
        __syncthreads();
    }
    int run = ps[t] - s;  // exclusive prefix
    for (int i = lo; i < hi; ++i) { ptr[i] = run; run += deg[i]; }
    if (t == 1023) ptr[N_NODES] = ps[1023];
}

__global__ __launch_bounds__(256) void fill_kernel(const int* __restrict__ ei, const int* __restrict__ ptr,
                                                   int* __restrict__ cur, int* __restrict__ srcs) {
    int i = blockIdx.x * 256 + threadIdx.x;
    int total = N_EDGES + N_NODES;
    if (i >= total) return;
    int s, d;
    if (i < N_EDGES) { s = ei[i]; d = ei[N_EDGES + i]; }
    else { s = d = i - N_EDGES; }
    int p = atomicAdd(&cur[d], 1);
    srcs[ptr[d] + p] = s;
}

// ---------------- per-layer kernels ----------------
// h = x @ W : (N,128)@(128,256) -> bf16 h (N,256), plus fused attention logits
__global__ __launch_bounds__(256) void gemm_kernel(const float* __restrict__ x, const float* __restrict__ W,
                                                   const float* __restrict__ as_, const float* __restrict__ ad_,
                                                   unsigned short* __restrict__ hb,
                                                   float* __restrict__ als, float* __restrict__ ald) {
    int t = threadIdx.x;
    int rg = t >> 6;          // row group 0..3 == wave id
    int lane = t & 63;
    int row0 = blockIdx.x * 32 + rg * 8;
    int c4 = lane * 4;        // 0..252

    const float* xr[8];
#pragma unroll
    for (int r = 0; r < 8; ++r) {
        int rr = row0 + r;
        if (rr >= N_NODES) rr = N_NODES - 1;
        xr[r] = x + (size_t)rr * 128;
    }

    float acc[8][4];
#pragma unroll
    for (int r = 0; r < 8; ++r)
#pragma unroll
        for (int j = 0; j < 4; ++j) acc[r][j] = 0.0f;

    for (int k = 0; k < 128; k += 4) {
        float4 xv[8];
#pragma unroll
        for (int r = 0; r < 8; ++r) xv[r] = *(const float4*)(xr[r] + k);
#pragma unroll
        for (int kk = 0; kk < 4; ++kk) {
            float4 w = *(const float4*)(W + (size_t)(k + kk) * 256 + c4);
#pragma unroll
            for (int r = 0; r < 8; ++r) {
                float xs = ((const float*)&xv[r])[kk];
                acc[r][0] += xs * w.x;
                acc[r][1] += xs * w.y;
                acc[r][2] += xs * w.z;
                acc[r][3] += xs * w.w;
            }
        }
    }

    float4 asv = *(const float4*)(as_ + c4);
    float4 adv = *(const float4*)(ad_ + c4);
#pragma unroll
    for (int r = 0; r < 8; ++r) {
        int rr = row0 + r;
        float ps = acc[r][0] * asv.x + acc[r][1] * asv.y + acc[r][2] * asv.z + acc[r][3] * asv.w;
        float pd = acc[r][0] * adv.x + acc[r][1] * adv.y + acc[r][2] * adv.z + acc[r][3] * adv.w;
#pragma unroll
        for (int o = 16; o; o >>= 1) {  // reduce within each 32-lane half (one head each)
            ps += __shfl_xor(ps, o);
            pd += __shfl_xor(pd, o);
        }
        if (rr < N_NODES) {
            if (lane == 0 || lane == 32) {
                int head = lane >> 5;
                als[(size_t)rr * 2 + head] = ps;
                ald[(size_t)rr * 2 + head] = pd;
            }
            ushort4 o4;
            o4.x = f2bf(acc[r][0]);
            o4.y = f2bf(acc[r][1]);
            o4.z = f2bf(acc[r][2]);
            o4.w = f2bf(acc[r][3]);
            *(ushort4*)(hb + (size_t)rr * 256 + c4) = o4;
        }
    }
}

// one wave per destination node; 4 lane-groups of 16 process 4 edges concurrently.
// Within a group: lane covers 16 consecutive bf16 cols (2x16B loads). gl<8 -> head0 cols, gl>=8 -> head1.
__global__ __launch_bounds__(256) void agg_kernel(const unsigned short* __restrict__ hb,
                                                  const float2* __restrict__ als, const float2* __restrict__ ald,
                                                  const int* __restrict__ ptr, const int* __restrict__ srcs,
                                                  const float* __restrict__ bias, float* __restrict__ agg) {
    int n = (blockIdx.x * 256 + threadIdx.x) >> 6;
    int lane = threadIdx.x & 63;
    if (n >= N_NODES) return;
    int b = ptr[n], e = ptr[n + 1];
    float2 ad = ald[n];
    int g = lane >> 4;        // edge slot 0..3
    int gl = lane & 15;       // lane within group
    int cb = gl * 16;         // col base 0..240
    bool head1 = gl >= 8;

    float acc[16];
#pragma unroll
    for (int j = 0; j < 16; ++j) acc[j] = 0.f;
    float d0 = 0.f, d1 = 0.f;

    int nit = (e - b + 3) >> 2;
#pragma unroll 2
    for (int it = 0; it < nit; ++it) {
        int idx = b + (it << 2) + g;
        bool act = idx < e;
        int s = srcs[act ? idx : e - 1];
        const unsigned short* hp = hb + (size_t)s * 256 + cb;
        us8 v0 = *(const us8*)hp;
        us8 v1 = *(const us8*)(hp + 8);
        float2 as2 = als[s];
        float x0 = act ? __expf(lrelu(as2.x + ad.x)) : 0.f;
        float x1 = act ? __expf(lrelu(as2.y + ad.y)) : 0.f;
        d0 += x0;
        d1 += x1;
        float w = head1 ? x1 : x0;
#pragma unroll
        for (int j = 0; j < 8; ++j) acc[j] += w * bf2f(v0[j]);
#pragma unroll
        for (int j = 0; j < 8; ++j) acc[8 + j] += w * bf2f(v1[j]);
    }

    // reduce across the 4 groups (lane xor 16, 32)
#pragma unroll
    for (int o = 16; o <= 32; o <<= 1) {
#pragma unroll
        for (int j = 0; j < 16; ++j) acc[j] += __shfl_xor(acc[j], o);
        d0 += __shfl_xor(d0, o);
        d1 += __shfl_xor(d1, o);
    }

    float inv = 1.0f / (head1 ? d1 : d0);
#pragma unroll
    for (int j = 0; j < 16; ++j) acc[j] *= inv;

    // mean over heads: pair lane gl with gl^8 (cols c and c+128)
    float oth[16];
#pragma unroll
    for (int j = 0; j < 16; ++j) oth[j] = __shfl_xor(acc[j], 8);

    if (g == 0 && !head1) {
        float* op = agg + (size_t)n * 128 + cb;
#pragma unroll
        for (int q = 0; q < 4; ++q) {
            float4 bv = *(const float4*)(bias + cb + q * 4);
            float4 res;
            res.x = 0.5f * (acc[q * 4 + 0] + oth[q * 4 + 0]) + bv.x;
            res.y = 0.5f * (acc[q * 4 + 1] + oth[q * 4 + 1]) + bv.y;
            res.z = 0.5f * (acc[q * 4 + 2] + oth[q * 4 + 2]) + bv.z;
            res.w = 0.5f * (acc[q * 4 + 3] + oth[q * 4 + 3]) + bv.w;
            *(float4*)(op + q * 4) = res;
        }
    }
}

// per-channel sum and sumsq
__global__ __launch_bounds__(256) void stats_kernel(const float* __restrict__ agg, float* __restrict__ stats) {
    __shared__ float ls[256], lq[256];
    int t = threadIdx.x;
    int c = t & 127, half = t >> 7;
    float s = 0.f, q = 0.f;
    for (int r = blockIdx.x * 2 + half; r < N_NODES; r += gridDim.x * 2) {
        float v = agg[(size_t)r * 128 + c];
        s += v;
        q += v * v;
    }
    ls[t] = s;
    lq[t] = q;
    __syncthreads();
    if (half == 0) {
        atomicAdd(&stats[c], s + ls[128 + c]);
        atomicAdd(&stats[128 + c], q + lq[128 + c]);
    }
}

// BN + ELU + residual
__global__ __launch_bounds__(256) void final_kernel(const float* __restrict__ agg, const float* __restrict__ res,
                                                    const float* __restrict__ gamma, const float* __restrict__ beta,
                                                    const float* __restrict__ stats, float* __restrict__ out) {
    const float invn = 1.0f / (float)N_NODES;
    int total = N_NODES * 32;  // float4 count
    for (int idx = blockIdx.x * 256 + threadIdx.x; idx < total; idx += gridDim.x * 256) {
        int c4 = (idx & 31) * 4;
        float4 v = ((const float4*)agg)[idx];
        float4 r = ((const float4*)res)[idx];
        const float* vp = (const float*)&v;
        const float* rp = (const float*)&r;
        float4 ov;
        float* op = (float*)&ov;
#pragma unroll
        for (int j = 0; j < 4; ++j) {
            int c = c4 + j;
            float mean = stats[c] * invn;
            float var = stats[128 + c] * invn - mean * mean;
            float is = rsqrtf(var + 1e-5f) * gamma[c];
            float val = (vp[j] - mean) * is + beta[c];
            val = val > 0.f ? val : (__expf(val) - 1.0f);
            op[j] = val + rp[j];
        }
        ((float4*)out)[idx] = ov;
    }
}

extern "C" void kernel_launch(void* const* d_in, const int* in_sizes, int n_in,
                              void* d_out, int out_size, void* d_ws, size_t ws_size,
                              hipStream_t stream) {
    const float* x0   = (const float*)d_in[0];
    const int* ei     = (const int*)d_in[1];
    const float* W    = (const float*)d_in[2];
    const float* asrc = (const float*)d_in[3];
    const float* adst = (const float*)d_in[4];
    const float* bias = (const float*)d_in[5];
    const float* gam  = (const float*)d_in[6];
    const float* bet  = (const float*)d_in[7];
    float* out = (float*)d_out;

    char* ws = (char*)d_ws;
    size_t off = 0;
    auto alloc = [&](size_t bytes) -> void* {
        void* p = ws + off;
        off += (bytes + 255) & ~(size_t)255;
        return p;
    };
    int* deg    = (int*)alloc((size_t)N_NODES * 4);
    int* cur    = (int*)alloc((size_t)N_NODES * 4);
    int* ptr    = (int*)alloc((size_t)(N_NODES + 1) * 4);
    int* srcs   = (int*)alloc((size_t)(N_EDGES + N_NODES) * 4);
    unsigned short* hb = (unsigned short*)alloc((size_t)N_NODES * 256 * 2);  // bf16 h
    float* als  = (float*)alloc((size_t)N_NODES * 2 * 4);
    float* ald  = (float*)alloc((size_t)N_NODES * 2 * 4);
    float* agg  = (float*)alloc((size_t)N_NODES * 128 * 4);
    float* x1   = (float*)alloc((size_t)N_NODES * 128 * 4);
    float* stats = (float*)alloc(512 * 4);

    hipMemsetAsync(deg, 0, (size_t)N_NODES * 4, stream);
    hipMemsetAsync(cur, 0, (size_t)N_NODES * 4, stream);
    hipMemsetAsync(stats, 0, 512 * 4, stream);

    int tot = N_EDGES + N_NODES;
    degree_kernel<<<(tot + 255) / 256, 256, 0, stream>>>(ei, deg);
    scan_kernel<<<1, 1024, 0, stream>>>(deg, ptr);
    fill_kernel<<<(tot + 255) / 256, 256, 0, stream>>>(ei, ptr, cur, srcs);

    for (int l = 0; l < 2; ++l) {
        const float* xin = l ? (const float*)x1 : x0;
        float* xout = l ? out : x1;
        gemm_kernel<<<(N_NODES + 31) / 32, 256, 0, stream>>>(
            xin, W + (size_t)l * 128 * 256, asrc + l * 256, adst + l * 256, hb, als, ald);
        agg_kernel<<<(N_NODES + 3) / 4, 256, 0, stream>>>(
            hb, (const float2*)als, (const float2*)ald, ptr, srcs, bias + l * 128, agg);
        stats_kernel<<<256, 256, 0, stream>>>(agg, stats + l * 256);
        final_kernel<<<2048, 256, 0, stream>>>(agg, xin, gam + l * 128, bet + l * 128, stats + l * 256, xout);
    }
}

// Round 4
// 426.512 us; speedup vs baseline: 1.6599x; 1.2804x over previous
//
#include <hip/hip_runtime.h>
#include <hip/hip_bf16.h>

#define N_NODES 50000
#define N_EDGES 800000
// C=128, H=2 -> h row = 256 cols

typedef unsigned short us8 __attribute__((ext_vector_type(8)));
typedef short s16x8 __attribute__((ext_vector_type(8)));
typedef float f32x4 __attribute__((ext_vector_type(4)));

static __device__ __forceinline__ float lrelu(float v) { return v > 0.0f ? v : 0.2f * v; }

static __device__ __forceinline__ unsigned short f2bf(float f) {
    unsigned int u = __float_as_uint(f);
    unsigned int r = (u + 0x7FFF + ((u >> 16) & 1)) >> 16;  // RNE
    return (unsigned short)r;
}
static __device__ __forceinline__ float bf2f(unsigned short u) {
    return __uint_as_float(((unsigned int)u) << 16);
}

// ---------------- CSR build ----------------
__global__ __launch_bounds__(256) void degree_kernel(const int* __restrict__ ei, int* __restrict__ deg) {
    int i = blockIdx.x * 256 + threadIdx.x;
    int total = N_EDGES + N_NODES;
    if (i >= total) return;
    int d = (i < N_EDGES) ? ei[N_EDGES + i] : (i - N_EDGES);
    atomicAdd(&deg[d], 1);
}

__global__ __launch_bounds__(1024) void scan_kernel(const int* __restrict__ deg, int* __restrict__ ptr) {
    __shared__ int ps[1024];
    int t = threadIdx.x;
    const int chunk = (N_NODES + 1023) / 1024;  // 49
    int lo = t * chunk;
    int hi = lo + chunk;
    if (lo > N_NODES) lo = N_NODES;
    if (hi > N_NODES) hi = N_NODES;
    int s = 0;
    for (int i = lo; i < hi; ++i) s += deg[i];
    ps[t] = s;
    __syncthreads();
    for (int o = 1; o < 1024; o <<= 1) {
        int v = (t >= o) ? ps[t - o] : 0;
        __syncthreads();
        ps[t] += v;
        __syncthreads();
    }
    int run = ps[t] - s;  // exclusive prefix
    for (int i = lo; i < hi; ++i) { ptr[i] = run; run += deg[i]; }
    if (t == 1023) ptr[N_NODES] = ps[1023];
}

__global__ __launch_bounds__(256) void fill_kernel(const int* __restrict__ ei, const int* __restrict__ ptr,
                                                   int* __restrict__ cur, int* __restrict__ srcs) {
    int i = blockIdx.x * 256 + threadIdx.x;
    int total = N_EDGES + N_NODES;
    if (i >= total) return;
    int s, d;
    if (i < N_EDGES) { s = ei[i]; d = ei[N_EDGES + i]; }
    else { s = d = i - N_EDGES; }
    int p = atomicAdd(&cur[d], 1);
    srcs[ptr[d] + p] = s;
}

// ---------------- precompute ----------------
// x (fp32) -> xb (bf16)
__global__ __launch_bounds__(256) void convert_kernel(const float* __restrict__ x, unsigned short* __restrict__ xb) {
    int total = N_NODES * 32;  // float4 count
    for (int i = blockIdx.x * 256 + threadIdx.x; i < total; i += gridDim.x * 256) {
        float4 v = ((const float4*)x)[i];
        ushort4 o;
        o.x = f2bf(v.x); o.y = f2bf(v.y); o.z = f2bf(v.z); o.w = f2bf(v.w);
        ((ushort4*)xb)[i] = o;
    }
}

// W[L][128][256] fp32 -> Wt[L][256][128] bf16 (B^T layout)
__global__ __launch_bounds__(256) void wtrans_kernel(const float* __restrict__ W, unsigned short* __restrict__ Wt) {
    int idx = blockIdx.x * 256 + threadIdx.x;  // 2*256*128 = 65536 total
    int l = idx >> 15;
    int c = (idx >> 7) & 255;
    int k = idx & 127;
    Wt[(size_t)l * 32768 + (size_t)c * 128 + k] = f2bf(W[(size_t)l * 32768 + (size_t)k * 256 + c]);
}

// ---------------- MFMA GEMM + fused attention logits ----------------
// h = x @ W : (N,128)@(128,256), bf16 inputs, fp32 acc. Block = 4 waves x 16 rows = 64 rows.
// Wt staged in LDS in two 32KB halves, XOR-swizzled (byte ^= (row&7)<<4) for conflict-free ds_read_b128.
__global__ __launch_bounds__(256) void gemm_kernel(const unsigned short* __restrict__ xb,
                                                   const unsigned short* __restrict__ Wt,
                                                   const float* __restrict__ as_, const float* __restrict__ ad_,
                                                   unsigned short* __restrict__ hb,
                                                   float2* __restrict__ als2, float2* __restrict__ ald2) {
    __shared__ unsigned short lw[128 * 128];  // 32KB: half of Wt (128 out-cols x 128 k), swizzled
    int t = threadIdx.x;
    int w = t >> 6, l = t & 63;
    int r0 = blockIdx.x * 64 + w * 16;
    int lrow = l & 15;   // M-row / N-col index within fragment
    int lk = l >> 4;     // k-group 0..3

    // A fragments: lane reads 8 contiguous bf16 at xb[r0+lrow][ka*32 + lk*8]
    int arow = r0 + lrow;
    if (arow >= N_NODES) arow = N_NODES - 1;
    s16x8 a[4];
#pragma unroll
    for (int ka = 0; ka < 4; ++ka)
        a[ka] = *(const s16x8*)(xb + (size_t)arow * 128 + ka * 32 + lk * 8);

    f32x4 acc[16];
#pragma unroll
    for (int i = 0; i < 16; ++i) acc[i] = (f32x4){0.f, 0.f, 0.f, 0.f};

    for (int half = 0; half < 2; ++half) {
        // stage 32KB = 2048 x 16B chunks; 256 threads x 8 chunks, swizzled dest
#pragma unroll
        for (int i = 0; i < 8; ++i) {
            int chunk = t + i * 256;            // 0..2047
            int row = chunk >> 4;               // 0..127 (16 chunks per 256B row)
            int kc = chunk & 15;
            uint4 v = *(const uint4*)(Wt + (size_t)(half * 128 + row) * 128 + kc * 8);
            int b = row * 256 + ((kc * 16) ^ ((row & 7) << 4));
            *(uint4*)((char*)lw + b) = v;
        }
        __syncthreads();
#pragma unroll
        for (int ct = 0; ct < 8; ++ct) {
            int row = ct * 16 + lrow;
#pragma unroll
            for (int ka = 0; ka < 4; ++ka) {
                int kb = (ka * 64 + lk * 16) ^ ((row & 7) << 4);
                s16x8 bf = *(const s16x8*)((const char*)lw + row * 256 + kb);
                acc[half * 8 + ct] = __builtin_amdgcn_mfma_f32_16x16x32_bf16(a[ka], bf, acc[half * 8 + ct], 0, 0, 0);
            }
        }
        __syncthreads();
    }

    // epilogue: C/D layout col = lane&15 (=lrow), row = (lane>>4)*4 + reg (=lk*4+reg)
    float av[16], dv[16];
#pragma unroll
    for (int ct = 0; ct < 16; ++ct) {
        av[ct] = as_[ct * 16 + lrow];
        dv[ct] = ad_[ct * 16 + lrow];
    }
#pragma unroll
    for (int reg = 0; reg < 4; ++reg) {
        int row = r0 + lk * 4 + reg;
        float s0 = 0.f, s1 = 0.f, d0 = 0.f, d1 = 0.f;
#pragma unroll
        for (int ct = 0; ct < 8; ++ct) {
            s0 += acc[ct][reg] * av[ct];
            d0 += acc[ct][reg] * dv[ct];
            s1 += acc[8 + ct][reg] * av[8 + ct];
            d1 += acc[8 + ct][reg] * dv[8 + ct];
        }
#pragma unroll
        for (int o = 1; o < 16; o <<= 1) {
            s0 += __shfl_xor(s0, o);
            s1 += __shfl_xor(s1, o);
            d0 += __shfl_xor(d0, o);
            d1 += __shfl_xor(d1, o);
        }
        if (row < N_NODES) {
            if (lrow == 0) {
                als2[row] = make_float2(s0, s1);
                ald2[row] = make_float2(d0, d1);
            }
            unsigned short* hp = hb + (size_t)row * 256 + lrow;
#pragma unroll
            for (int ct = 0; ct < 16; ++ct) hp[ct * 16] = f2bf(acc[ct][reg]);
        }
    }
}

// one wave per destination node; 4 lane-groups of 16 process 4 edges concurrently.
__global__ __launch_bounds__(256) void agg_kernel(const unsigned short* __restrict__ hb,
                                                  const float2* __restrict__ als, const float2* __restrict__ ald,
                                                  const int* __restrict__ ptr, const int* __restrict__ srcs,
                                                  const float* __restrict__ bias, float* __restrict__ agg) {
    int n = (blockIdx.x * 256 + threadIdx.x) >> 6;
    int lane = threadIdx.x & 63;
    if (n >= N_NODES) return;
    int b = ptr[n], e = ptr[n + 1];
    float2 ad = ald[n];
    int g = lane >> 4;        // edge slot 0..3
    int gl = lane & 15;       // lane within group
    int cb = gl * 16;         // col base 0..240
    bool head1 = gl >= 8;

    float acc[16];
#pragma unroll
    for (int j = 0; j < 16; ++j) acc[j] = 0.f;
    float d0 = 0.f, d1 = 0.f;

    int nit = (e - b + 3) >> 2;
#pragma unroll 2
    for (int it = 0; it < nit; ++it) {
        int idx = b + (it << 2) + g;
        bool act = idx < e;
        int s = srcs[act ? idx : e - 1];
        const unsigned short* hp = hb + (size_t)s * 256 + cb;
        us8 v0 = *(const us8*)hp;
        us8 v1 = *(const us8*)(hp + 8);
        float2 as2 = als[s];
        float x0 = act ? __expf(lrelu(as2.x + ad.x)) : 0.f;
        float x1 = act ? __expf(lrelu(as2.y + ad.y)) : 0.f;
        d0 += x0;
        d1 += x1;
        float w = head1 ? x1 : x0;
#pragma unroll
        for (int j = 0; j < 8; ++j) acc[j] += w * bf2f(v0[j]);
#pragma unroll
        for (int j = 0; j < 8; ++j) acc[8 + j] += w * bf2f(v1[j]);
    }

    // reduce across the 4 groups (lane xor 16, 32)
#pragma unroll
    for (int o = 16; o <= 32; o <<= 1) {
#pragma unroll
        for (int j = 0; j < 16; ++j) acc[j] += __shfl_xor(acc[j], o);
        d0 += __shfl_xor(d0, o);
        d1 += __shfl_xor(d1, o);
    }

    float inv = 1.0f / (head1 ? d1 : d0);
#pragma unroll
    for (int j = 0; j < 16; ++j) acc[j] *= inv;

    // mean over heads: pair lane gl with gl^8 (cols c and c+128)
    float oth[16];
#pragma unroll
    for (int j = 0; j < 16; ++j) oth[j] = __shfl_xor(acc[j], 8);

    if (g == 0 && !head1) {
        float* op = agg + (size_t)n * 128 + cb;
#pragma unroll
        for (int q = 0; q < 4; ++q) {
            float4 bv = *(const float4*)(bias + cb + q * 4);
            float4 res;
            res.x = 0.5f * (acc[q * 4 + 0] + oth[q * 4 + 0]) + bv.x;
            res.y = 0.5f * (acc[q * 4 + 1] + oth[q * 4 + 1]) + bv.y;
            res.z = 0.5f * (acc[q * 4 + 2] + oth[q * 4 + 2]) + bv.z;
            res.w = 0.5f * (acc[q * 4 + 3] + oth[q * 4 + 3]) + bv.w;
            *(float4*)(op + q * 4) = res;
        }
    }
}

// per-channel sum and sumsq
__global__ __launch_bounds__(256) void stats_kernel(const float* __restrict__ agg, float* __restrict__ stats) {
    __shared__ float ls[256], lq[256];
    int t = threadIdx.x;
    int c = t & 127, half = t >> 7;
    float s = 0.f, q = 0.f;
    for (int r = blockIdx.x * 2 + half; r < N_NODES; r += gridDim.x * 2) {
        float v = agg[(size_t)r * 128 + c];
        s += v;
        q += v * v;
    }
    ls[t] = s;
    lq[t] = q;
    __syncthreads();
    if (half == 0) {
        atomicAdd(&stats[c], s + ls[128 + c]);
        atomicAdd(&stats[128 + c], q + lq[128 + c]);
    }
}

// BN + ELU + residual (+ optional bf16 copy of the output for the next layer's GEMM)
__global__ __launch_bounds__(256) void final_kernel(const float* __restrict__ agg, const float* __restrict__ res,
                                                    const float* __restrict__ gamma, const float* __restrict__ beta,
                                                    const float* __restrict__ stats, float* __restrict__ out,
                                                    unsigned short* __restrict__ xb_out) {
    const float invn = 1.0f / (float)N_NODES;
    int total = N_NODES * 32;  // float4 count
    for (int idx = blockIdx.x * 256 + threadIdx.x; idx < total; idx += gridDim.x * 256) {
        int c4 = (idx & 31) * 4;
        float4 v = ((const float4*)agg)[idx];
        float4 r = ((const float4*)res)[idx];
        const float* vp = (const float*)&v;
        const float* rp = (const float*)&r;
        float4 ov;
        float* op = (float*)&ov;
#pragma unroll
        for (int j = 0; j < 4; ++j) {
            int c = c4 + j;
            float mean = stats[c] * invn;
            float var = stats[128 + c] * invn - mean * mean;
            float is = rsqrtf(var + 1e-5f) * gamma[c];
            float val = (vp[j] - mean) * is + beta[c];
            val = val > 0.f ? val : (__expf(val) - 1.0f);
            op[j] = val + rp[j];
        }
        ((float4*)out)[idx] = ov;
        if (xb_out) {
            ushort4 ob;
            ob.x = f2bf(ov.x); ob.y = f2bf(ov.y); ob.z = f2bf(ov.z); ob.w = f2bf(ov.w);
            ((ushort4*)xb_out)[idx] = ob;
        }
    }
}

extern "C" void kernel_launch(void* const* d_in, const int* in_sizes, int n_in,
                              void* d_out, int out_size, void* d_ws, size_t ws_size,
                              hipStream_t stream) {
    const float* x0   = (const float*)d_in[0];
    const int* ei     = (const int*)d_in[1];
    const float* W    = (const float*)d_in[2];
    const float* asrc = (const float*)d_in[3];
    const float* adst = (const float*)d_in[4];
    const float* bias = (const float*)d_in[5];
    const float* gam  = (const float*)d_in[6];
    const float* bet  = (const float*)d_in[7];
    float* out = (float*)d_out;

    char* ws = (char*)d_ws;
    size_t off = 0;
    auto alloc = [&](size_t bytes) -> void* {
        void* p = ws + off;
        off += (bytes + 255) & ~(size_t)255;
        return p;
    };
    int* deg    = (int*)alloc((size_t)N_NODES * 4);
    int* cur    = (int*)alloc((size_t)N_NODES * 4);
    int* ptr    = (int*)alloc((size_t)(N_NODES + 1) * 4);
    int* srcs   = (int*)alloc((size_t)(N_EDGES + N_NODES) * 4);
    unsigned short* hb = (unsigned short*)alloc((size_t)N_NODES * 256 * 2);  // bf16 h
    unsigned short* xb = (unsigned short*)alloc((size_t)N_NODES * 128 * 2);  // bf16 x (current layer input)
    unsigned short* Wt = (unsigned short*)alloc((size_t)2 * 256 * 128 * 2);  // bf16 W^T, both layers
    float* als  = (float*)alloc((size_t)N_NODES * 2 * 4);
    float* ald  = (float*)alloc((size_t)N_NODES * 2 * 4);
    float* agg  = (float*)alloc((size_t)N_NODES * 128 * 4);
    float* x1   = (float*)alloc((size_t)N_NODES * 128 * 4);
    float* stats = (float*)alloc(512 * 4);

    hipMemsetAsync(deg, 0, (size_t)N_NODES * 4, stream);
    hipMemsetAsync(cur, 0, (size_t)N_NODES * 4, stream);
    hipMemsetAsync(stats, 0, 512 * 4, stream);

    int tot = N_EDGES + N_NODES;
    degree_kernel<<<(tot + 255) / 256, 256, 0, stream>>>(ei, deg);
    scan_kernel<<<1, 1024, 0, stream>>>(deg, ptr);
    fill_kernel<<<(tot + 255) / 256, 256, 0, stream>>>(ei, ptr, cur, srcs);
    convert_kernel<<<2048, 256, 0, stream>>>(x0, xb);
    wtrans_kernel<<<256, 256, 0, stream>>>(W, Wt);

    for (int l = 0; l < 2; ++l) {
        const float* xin = l ? (const float*)x1 : x0;
        float* xout = l ? out : x1;
        gemm_kernel<<<(N_NODES + 63) / 64, 256, 0, stream>>>(
            xb, Wt + (size_t)l * 32768, asrc + l * 256, adst + l * 256, hb,
            (float2*)als, (float2*)ald);
        agg_kernel<<<(N_NODES + 3) / 4, 256, 0, stream>>>(
            hb, (const float2*)als, (const float2*)ald, ptr, srcs, bias + l * 128, agg);
        stats_kernel<<<256, 256, 0, stream>>>(agg, stats + l * 256);
        final_kernel<<<2048, 256, 0, stream>>>(agg, xin, gam + l * 128, bet + l * 128, stats + l * 256,
                                               xout, l == 0 ? xb : (unsigned short*)nullptr);
    }
}

// Round 5
// 389.755 us; speedup vs baseline: 1.8164x; 1.0943x over previous
//
#include <hip/hip_runtime.h>
#include <hip/hip_bf16.h>

#define N_NODES 50000
#define N_EDGES 800000
#define NB_SCAN ((N_NODES + 255) / 256)   // 196
// C=128, H=2 -> h row = 256 cols

typedef unsigned short us8 __attribute__((ext_vector_type(8)));
typedef short s16x8 __attribute__((ext_vector_type(8)));
typedef float f32x4 __attribute__((ext_vector_type(4)));

static __device__ __forceinline__ float lrelu(float v) { return v > 0.0f ? v : 0.2f * v; }

static __device__ __forceinline__ unsigned short f2bf(float f) {
    unsigned int u = __float_as_uint(f);
    unsigned int r = (u + 0x7FFF + ((u >> 16) & 1)) >> 16;  // RNE
    return (unsigned short)r;
}
static __device__ __forceinline__ float bf2f(unsigned short u) {
    return __uint_as_float(((unsigned int)u) << 16);
}

// ---------------- CSR build ----------------
__global__ __launch_bounds__(256) void degree_kernel(const int* __restrict__ ei, int* __restrict__ deg) {
    int i = blockIdx.x * 256 + threadIdx.x;
    int total = N_EDGES + N_NODES;
    if (i >= total) return;
    int d = (i < N_EDGES) ? ei[N_EDGES + i] : (i - N_EDGES);
    atomicAdd(&deg[d], 1);
}

// per-block sums of deg (256 elements per block)
__global__ __launch_bounds__(256) void bsum_kernel(const int* __restrict__ deg, int* __restrict__ bsum) {
    __shared__ int ws[4];
    int i = blockIdx.x * 256 + threadIdx.x;
    int v = (i < N_NODES) ? deg[i] : 0;
    int s = v;
#pragma unroll
    for (int o = 32; o; o >>= 1) s += __shfl_xor(s, o);
    if ((threadIdx.x & 63) == 0) ws[threadIdx.x >> 6] = s;
    __syncthreads();
    if (threadIdx.x == 0) bsum[blockIdx.x] = ws[0] + ws[1] + ws[2] + ws[3];
}

// scan the 196 block sums -> exclusive block offsets + total
__global__ __launch_bounds__(256) void bscan_kernel(const int* __restrict__ bsum, int* __restrict__ boff,
                                                    int* __restrict__ ptr) {
    __shared__ int ps[256];
    int t = threadIdx.x;
    int v = (t < NB_SCAN) ? bsum[t] : 0;
    ps[t] = v;
    __syncthreads();
#pragma unroll
    for (int o = 1; o < 256; o <<= 1) {
        int u = (t >= o) ? ps[t - o] : 0;
        __syncthreads();
        ps[t] += u;
        __syncthreads();
    }
    if (t < NB_SCAN) boff[t] = ps[t] - v;  // exclusive
    if (t == NB_SCAN - 1) ptr[N_NODES] = ps[t];
}

// in-block scan + add block offset -> ptr
__global__ __launch_bounds__(256) void ptr_kernel(const int* __restrict__ deg, const int* __restrict__ boff,
                                                  int* __restrict__ ptr) {
    __shared__ int ps[256];
    int t = threadIdx.x;
    int i = blockIdx.x * 256 + t;
    int v = (i < N_NODES) ? deg[i] : 0;
    ps[t] = v;
    __syncthreads();
#pragma unroll
    for (int o = 1; o < 256; o <<= 1) {
        int u = (t >= o) ? ps[t - o] : 0;
        __syncthreads();
        ps[t] += u;
        __syncthreads();
    }
    if (i < N_NODES) ptr[i] = boff[blockIdx.x] + ps[t] - v;
}

__global__ __launch_bounds__(256) void fill_kernel(const int* __restrict__ ei, const int* __restrict__ ptr,
                                                   int* __restrict__ cur, int* __restrict__ srcs) {
    int i = blockIdx.x * 256 + threadIdx.x;
    int total = N_EDGES + N_NODES;
    if (i >= total) return;
    int s, d;
    if (i < N_EDGES) { s = ei[i]; d = ei[N_EDGES + i]; }
    else { s = d = i - N_EDGES; }
    int p = atomicAdd(&cur[d], 1);
    srcs[ptr[d] + p] = s;
}

// ---------------- precompute ----------------
__global__ __launch_bounds__(256) void convert_kernel(const float* __restrict__ x, unsigned short* __restrict__ xb) {
    int total = N_NODES * 32;  // float4 count
    for (int i = blockIdx.x * 256 + threadIdx.x; i < total; i += gridDim.x * 256) {
        float4 v = ((const float4*)x)[i];
        ushort4 o;
        o.x = f2bf(v.x); o.y = f2bf(v.y); o.z = f2bf(v.z); o.w = f2bf(v.w);
        ((ushort4*)xb)[i] = o;
    }
}

// W[L][128][256] fp32 -> Wt[L][256][128] bf16 (B^T layout)
__global__ __launch_bounds__(256) void wtrans_kernel(const float* __restrict__ W, unsigned short* __restrict__ Wt) {
    int idx = blockIdx.x * 256 + threadIdx.x;  // 2*256*128 = 65536 total
    int l = idx >> 15;
    int c = (idx >> 7) & 255;
    int k = idx & 127;
    Wt[(size_t)l * 32768 + (size_t)c * 128 + k] = f2bf(W[(size_t)l * 32768 + (size_t)k * 256 + c]);
}

// ---------------- MFMA GEMM + fused attention logits ----------------
__global__ __launch_bounds__(256) void gemm_kernel(const unsigned short* __restrict__ xb,
                                                   const unsigned short* __restrict__ Wt,
                                                   const float* __restrict__ as_, const float* __restrict__ ad_,
                                                   unsigned short* __restrict__ hb,
                                                   float2* __restrict__ als2, float2* __restrict__ ald2) {
    __shared__ unsigned short lw[128 * 128];  // 32KB: half of Wt (128 out-cols x 128 k), swizzled
    int t = threadIdx.x;
    int w = t >> 6, l = t & 63;
    int r0 = blockIdx.x * 64 + w * 16;
    int lrow = l & 15;   // M-row / N-col index within fragment
    int lk = l >> 4;     // k-group 0..3

    int arow = r0 + lrow;
    if (arow >= N_NODES) arow = N_NODES - 1;
    s16x8 a[4];
#pragma unroll
    for (int ka = 0; ka < 4; ++ka)
        a[ka] = *(const s16x8*)(xb + (size_t)arow * 128 + ka * 32 + lk * 8);

    f32x4 acc[16];
#pragma unroll
    for (int i = 0; i < 16; ++i) acc[i] = (f32x4){0.f, 0.f, 0.f, 0.f};

    for (int half = 0; half < 2; ++half) {
#pragma unroll
        for (int i = 0; i < 8; ++i) {
            int chunk = t + i * 256;            // 0..2047
            int row = chunk >> 4;               // 0..127
            int kc = chunk & 15;
            uint4 v = *(const uint4*)(Wt + (size_t)(half * 128 + row) * 128 + kc * 8);
            int b = row * 256 + ((kc * 16) ^ ((row & 7) << 4));
            *(uint4*)((char*)lw + b) = v;
        }
        __syncthreads();
#pragma unroll
        for (int ct = 0; ct < 8; ++ct) {
            int row = ct * 16 + lrow;
#pragma unroll
            for (int ka = 0; ka < 4; ++ka) {
                int kb = (ka * 64 + lk * 16) ^ ((row & 7) << 4);
                s16x8 bf = *(const s16x8*)((const char*)lw + row * 256 + kb);
                acc[half * 8 + ct] = __builtin_amdgcn_mfma_f32_16x16x32_bf16(a[ka], bf, acc[half * 8 + ct], 0, 0, 0);
            }
        }
        __syncthreads();
    }

    // epilogue: C/D layout col = lane&15 (=lrow), row = lk*4+reg
    float av[16], dv[16];
#pragma unroll
    for (int ct = 0; ct < 16; ++ct) {
        av[ct] = as_[ct * 16 + lrow];
        dv[ct] = ad_[ct * 16 + lrow];
    }
#pragma unroll
    for (int reg = 0; reg < 4; ++reg) {
        int row = r0 + lk * 4 + reg;
        float s0 = 0.f, s1 = 0.f, d0 = 0.f, d1 = 0.f;
#pragma unroll
        for (int ct = 0; ct < 8; ++ct) {
            s0 += acc[ct][reg] * av[ct];
            d0 += acc[ct][reg] * dv[ct];
            s1 += acc[8 + ct][reg] * av[8 + ct];
            d1 += acc[8 + ct][reg] * dv[8 + ct];
        }
#pragma unroll
        for (int o = 1; o < 16; o <<= 1) {
            s0 += __shfl_xor(s0, o);
            s1 += __shfl_xor(s1, o);
            d0 += __shfl_xor(d0, o);
            d1 += __shfl_xor(d1, o);
        }
        if (row < N_NODES) {
            if (lrow == 0) {
                als2[row] = make_float2(s0, s1);
                ald2[row] = make_float2(d0, d1);
            }
            unsigned short* hp = hb + (size_t)row * 256 + lrow;
#pragma unroll
            for (int ct = 0; ct < 16; ++ct) hp[ct * 16] = f2bf(acc[ct][reg]);
        }
    }
}

// one wave per destination node; 8 lane-groups of 8 process 8 edges concurrently.
// Within a group: lane covers 32 consecutive bf16 cols (4x16B loads). gl<4 -> head0, gl>=4 -> head1.
__global__ __launch_bounds__(256) void agg_kernel(const unsigned short* __restrict__ hb,
                                                  const float2* __restrict__ als, const float2* __restrict__ ald,
                                                  const int* __restrict__ ptr, const int* __restrict__ srcs,
                                                  const float* __restrict__ bias, float* __restrict__ agg) {
    int n = (blockIdx.x * 256 + threadIdx.x) >> 6;
    int lane = threadIdx.x & 63;
    if (n >= N_NODES) return;
    int b = ptr[n], e = ptr[n + 1];
    float2 ad = ald[n];
    int g = lane >> 3;        // edge slot 0..7
    int gl = lane & 7;        // lane within group
    int cb = gl * 32;         // col base 0..224
    bool head1 = gl >= 4;

    float acc[32];
#pragma unroll
    for (int j = 0; j < 32; ++j) acc[j] = 0.f;
    float d0 = 0.f, d1 = 0.f;

    int nit = (e - b + 7) >> 3;
#pragma unroll 2
    for (int it = 0; it < nit; ++it) {
        int idx = b + (it << 3) + g;
        bool act = idx < e;
        int s = srcs[act ? idx : e - 1];
        const unsigned short* hp = hb + (size_t)s * 256 + cb;
        us8 v0 = *(const us8*)hp;
        us8 v1 = *(const us8*)(hp + 8);
        us8 v2 = *(const us8*)(hp + 16);
        us8 v3 = *(const us8*)(hp + 24);
        float2 as2 = als[s];
        float x0 = act ? __expf(lrelu(as2.x + ad.x)) : 0.f;
        float x1 = act ? __expf(lrelu(as2.y + ad.y)) : 0.f;
        d0 += x0;
        d1 += x1;
        float w = head1 ? x1 : x0;
#pragma unroll
        for (int j = 0; j < 8; ++j) acc[j] += w * bf2f(v0[j]);
#pragma unroll
        for (int j = 0; j < 8; ++j) acc[8 + j] += w * bf2f(v1[j]);
#pragma unroll
        for (int j = 0; j < 8; ++j) acc[16 + j] += w * bf2f(v2[j]);
#pragma unroll
        for (int j = 0; j < 8; ++j) acc[24 + j] += w * bf2f(v3[j]);
    }

    // reduce across the 8 groups (lane xor 8, 16, 32)
#pragma unroll
    for (int o = 8; o <= 32; o <<= 1) {
#pragma unroll
        for (int j = 0; j < 32; ++j) acc[j] += __shfl_xor(acc[j], o);
        d0 += __shfl_xor(d0, o);
        d1 += __shfl_xor(d1, o);
    }

    float inv = 1.0f / (head1 ? d1 : d0);
#pragma unroll
    for (int j = 0; j < 32; ++j) acc[j] *= inv;

    // mean over heads: pair lane gl with gl^4 (cols c and c+128)
    float oth[32];
#pragma unroll
    for (int j = 0; j < 32; ++j) oth[j] = __shfl_xor(acc[j], 4);

    if (g == 0 && !head1) {
        float* op = agg + (size_t)n * 128 + cb;
#pragma unroll
        for (int q = 0; q < 8; ++q) {
            float4 bv = *(const float4*)(bias + cb + q * 4);
            float4 res;
            res.x = 0.5f * (acc[q * 4 + 0] + oth[q * 4 + 0]) + bv.x;
            res.y = 0.5f * (acc[q * 4 + 1] + oth[q * 4 + 1]) + bv.y;
            res.z = 0.5f * (acc[q * 4 + 2] + oth[q * 4 + 2]) + bv.z;
            res.w = 0.5f * (acc[q * 4 + 3] + oth[q * 4 + 3]) + bv.w;
            *(float4*)(op + q * 4) = res;
        }
    }
}

// per-channel sum and sumsq
__global__ __launch_bounds__(256) void stats_kernel(const float* __restrict__ agg, float* __restrict__ stats) {
    __shared__ float ls[256], lq[256];
    int t = threadIdx.x;
    int c = t & 127, half = t >> 7;
    float s = 0.f, q = 0.f;
    for (int r = blockIdx.x * 2 + half; r < N_NODES; r += gridDim.x * 2) {
        float v = agg[(size_t)r * 128 + c];
        s += v;
        q += v * v;
    }
    ls[t] = s;
    lq[t] = q;
    __syncthreads();
    if (half == 0) {
        atomicAdd(&stats[c], s + ls[128 + c]);
        atomicAdd(&stats[128 + c], q + lq[128 + c]);
    }
}

// BN + ELU + residual (+ optional bf16 copy for next layer's GEMM input)
__global__ __launch_bounds__(256) void final_kernel(const float* __restrict__ agg, const float* __restrict__ res,
                                                    const float* __restrict__ gamma, const float* __restrict__ beta,
                                                    const float* __restrict__ stats, float* __restrict__ out,
                                                    unsigned short* __restrict__ xb_out) {
    const float invn = 1.0f / (float)N_NODES;
    int total = N_NODES * 32;  // float4 count
    for (int idx = blockIdx.x * 256 + threadIdx.x; idx < total; idx += gridDim.x * 256) {
        int c4 = (idx & 31) * 4;
        float4 v = ((const float4*)agg)[idx];
        float4 r = ((const float4*)res)[idx];
        const float* vp = (const float*)&v;
        const float* rp = (const float*)&r;
        float4 ov;
        float* op = (float*)&ov;
#pragma unroll
        for (int j = 0; j < 4; ++j) {
            int c = c4 + j;
            float mean = stats[c] * invn;
            float var = stats[128 + c] * invn - mean * mean;
            float is = rsqrtf(var + 1e-5f) * gamma[c];
            float val = (vp[j] - mean) * is + beta[c];
            val = val > 0.f ? val : (__expf(val) - 1.0f);
            op[j] = val + rp[j];
        }
        ((float4*)out)[idx] = ov;
        if (xb_out) {
            ushort4 ob;
            ob.x = f2bf(ov.x); ob.y = f2bf(ov.y); ob.z = f2bf(ov.z); ob.w = f2bf(ov.w);
            ((ushort4*)xb_out)[idx] = ob;
        }
    }
}

extern "C" void kernel_launch(void* const* d_in, const int* in_sizes, int n_in,
                              void* d_out, int out_size, void* d_ws, size_t ws_size,
                              hipStream_t stream) {
    const float* x0   = (const float*)d_in[0];
    const int* ei     = (const int*)d_in[1];
    const float* W    = (const float*)d_in[2];
    const float* asrc = (const float*)d_in[3];
    const float* adst = (const float*)d_in[4];
    const float* bias = (const float*)d_in[5];
    const float* gam  = (const float*)d_in[6];
    const float* bet  = (const float*)d_in[7];
    float* out = (float*)d_out;

    char* ws = (char*)d_ws;
    size_t off = 0;
    auto alloc = [&](size_t bytes) -> void* {
        void* p = ws + off;
        off += (bytes + 255) & ~(size_t)255;
        return p;
    };
    int* deg    = (int*)alloc((size_t)N_NODES * 4);
    int* cur    = (int*)alloc((size_t)N_NODES * 4);
    int* ptr    = (int*)alloc((size_t)(N_NODES + 1) * 4);
    int* bsum   = (int*)alloc((size_t)NB_SCAN * 4);
    int* boff   = (int*)alloc((size_t)NB_SCAN * 4);
    int* srcs   = (int*)alloc((size_t)(N_EDGES + N_NODES) * 4);
    unsigned short* hb = (unsigned short*)alloc((size_t)N_NODES * 256 * 2);  // bf16 h
    unsigned short* xb = (unsigned short*)alloc((size_t)N_NODES * 128 * 2);  // bf16 layer input
    unsigned short* Wt = (unsigned short*)alloc((size_t)2 * 256 * 128 * 2);  // bf16 W^T
    float* als  = (float*)alloc((size_t)N_NODES * 2 * 4);
    float* ald  = (float*)alloc((size_t)N_NODES * 2 * 4);
    float* agg  = (float*)alloc((size_t)N_NODES * 128 * 4);
    float* x1   = (float*)alloc((size_t)N_NODES * 128 * 4);
    float* stats = (float*)alloc(512 * 4);

    hipMemsetAsync(deg, 0, (size_t)N_NODES * 4, stream);
    hipMemsetAsync(cur, 0, (size_t)N_NODES * 4, stream);
    hipMemsetAsync(stats, 0, 512 * 4, stream);

    int tot = N_EDGES + N_NODES;
    degree_kernel<<<(tot + 255) / 256, 256, 0, stream>>>(ei, deg);
    bsum_kernel<<<NB_SCAN, 256, 0, stream>>>(deg, bsum);
    bscan_kernel<<<1, 256, 0, stream>>>(bsum, boff, ptr);
    ptr_kernel<<<NB_SCAN, 256, 0, stream>>>(deg, boff, ptr);
    fill_kernel<<<(tot + 255) / 256, 256, 0, stream>>>(ei, ptr, cur, srcs);
    convert_kernel<<<2048, 256, 0, stream>>>(x0, xb);
    wtrans_kernel<<<256, 256, 0, stream>>>(W, Wt);

    for (int l = 0; l < 2; ++l) {
        const float* xin = l ? (const float*)x1 : x0;
        float* xout = l ? out : x1;
        gemm_kernel<<<(N_NODES + 63) / 64, 256, 0, stream>>>(
            xb, Wt + (size_t)l * 32768, asrc + l * 256, adst + l * 256, hb,
            (float2*)als, (float2*)ald);
        agg_kernel<<<(N_NODES + 3) / 4, 256, 0, stream>>>(
            hb, (const float2*)als, (const float2*)ald, ptr, srcs, bias + l * 128, agg);
        stats_kernel<<<256, 256, 0, stream>>>(agg, stats + l * 256);
        final_kernel<<<2048, 256, 0, stream>>>(agg, xin, gam + l * 128, bet + l * 128, stats + l * 256,
                                               xout, l == 0 ? xb : (unsigned short*)nullptr);
    }
}

// Round 6
// 378.319 us; speedup vs baseline: 1.8714x; 1.0302x over previous
//
#include <hip/hip_runtime.h>
#include <hip/hip_bf16.h>

#define N_NODES 50000
#define N_EDGES 800000
#define NB_SCAN ((N_NODES + 255) / 256)   // 196
// C=128, H=2

typedef unsigned short us8 __attribute__((ext_vector_type(8)));
typedef short s16x8 __attribute__((ext_vector_type(8)));
typedef float f32x4 __attribute__((ext_vector_type(4)));

static __device__ __forceinline__ float lrelu(float v) { return v > 0.0f ? v : 0.2f * v; }

static __device__ __forceinline__ unsigned short f2bf(float f) {
    unsigned int u = __float_as_uint(f);
    unsigned int r = (u + 0x7FFF + ((u >> 16) & 1)) >> 16;  // RNE
    return (unsigned short)r;
}
static __device__ __forceinline__ float bf2f(unsigned short u) {
    return __uint_as_float(((unsigned int)u) << 16);
}

// ---------------- CSR build ----------------
__global__ __launch_bounds__(256) void degree_kernel(const int* __restrict__ ei, int* __restrict__ deg) {
    int i = blockIdx.x * 256 + threadIdx.x;
    int total = N_EDGES + N_NODES;
    if (i >= total) return;
    int d = (i < N_EDGES) ? ei[N_EDGES + i] : (i - N_EDGES);
    atomicAdd(&deg[d], 1);
}

__global__ __launch_bounds__(256) void bsum_kernel(const int* __restrict__ deg, int* __restrict__ bsum) {
    __shared__ int ws[4];
    int i = blockIdx.x * 256 + threadIdx.x;
    int v = (i < N_NODES) ? deg[i] : 0;
    int s = v;
#pragma unroll
    for (int o = 32; o; o >>= 1) s += __shfl_xor(s, o);
    if ((threadIdx.x & 63) == 0) ws[threadIdx.x >> 6] = s;
    __syncthreads();
    if (threadIdx.x == 0) bsum[blockIdx.x] = ws[0] + ws[1] + ws[2] + ws[3];
}

__global__ __launch_bounds__(256) void bscan_kernel(const int* __restrict__ bsum, int* __restrict__ boff,
                                                    int* __restrict__ ptr) {
    __shared__ int ps[256];
    int t = threadIdx.x;
    int v = (t < NB_SCAN) ? bsum[t] : 0;
    ps[t] = v;
    __syncthreads();
#pragma unroll
    for (int o = 1; o < 256; o <<= 1) {
        int u = (t >= o) ? ps[t - o] : 0;
        __syncthreads();
        ps[t] += u;
        __syncthreads();
    }
    if (t < NB_SCAN) boff[t] = ps[t] - v;
    if (t == NB_SCAN - 1) ptr[N_NODES] = ps[t];
}

__global__ __launch_bounds__(256) void ptr_kernel(const int* __restrict__ deg, const int* __restrict__ boff,
                                                  int* __restrict__ ptr) {
    __shared__ int ps[256];
    int t = threadIdx.x;
    int i = blockIdx.x * 256 + t;
    int v = (i < N_NODES) ? deg[i] : 0;
    ps[t] = v;
    __syncthreads();
#pragma unroll
    for (int o = 1; o < 256; o <<= 1) {
        int u = (t >= o) ? ps[t - o] : 0;
        __syncthreads();
        ps[t] += u;
        __syncthreads();
    }
    if (i < N_NODES) ptr[i] = boff[blockIdx.x] + ps[t] - v;
}

__global__ __launch_bounds__(256) void fill_kernel(const int* __restrict__ ei, const int* __restrict__ ptr,
                                                   int* __restrict__ cur, int* __restrict__ srcs) {
    int i = blockIdx.x * 256 + threadIdx.x;
    int total = N_EDGES + N_NODES;
    if (i >= total) return;
    int s, d;
    if (i < N_EDGES) { s = ei[i]; d = ei[N_EDGES + i]; }
    else { s = d = i - N_EDGES; }
    int p = atomicAdd(&cur[d], 1);
    srcs[ptr[d] + p] = s;
}

// ---------------- precompute ----------------
__global__ __launch_bounds__(256) void convert_kernel(const float* __restrict__ x, unsigned short* __restrict__ xb) {
    int total = N_NODES * 32;
    for (int i = blockIdx.x * 256 + threadIdx.x; i < total; i += gridDim.x * 256) {
        float4 v = ((const float4*)x)[i];
        ushort4 o;
        o.x = f2bf(v.x); o.y = f2bf(v.y); o.z = f2bf(v.z); o.w = f2bf(v.w);
        ((ushort4*)xb)[i] = o;
    }
}

// wa_s[l][head][k] = sum_c W[l][k][head*128+c]*as[l][head][c]; same for wa_d. blockIdx = l.
__global__ __launch_bounds__(256) void wa_kernel(const float* __restrict__ W, const float* __restrict__ as_,
                                                 const float* __restrict__ ad_, float* __restrict__ was,
                                                 float* __restrict__ wad) {
    int l = blockIdx.x;
    int t = threadIdx.x;
    int head = t >> 7, k = t & 127;
    const float* wr = W + (size_t)l * 32768 + (size_t)k * 256 + head * 128;
    const float* ar = as_ + l * 256 + head * 128;
    const float* dr = ad_ + l * 256 + head * 128;
    float s = 0.f, d = 0.f;
    for (int c = 0; c < 128; ++c) {
        float wv = wr[c];
        s += wv * ar[c];
        d += wv * dr[c];
    }
    was[l * 256 + t] = s;
    wad[l * 256 + t] = d;
}

// Mt[l][c][kc] = bf16(0.5*W[l][kc&127][(kc>>7)*128 + c])  (B^T layout, 128 cols x 256 k)
__global__ __launch_bounds__(256) void mt_kernel(const float* __restrict__ W, unsigned short* __restrict__ Mt) {
    int idx = blockIdx.x * 256 + threadIdx.x;  // 65536
    int l = idx >> 15, c = (idx >> 8) & 127, kc = idx & 255;
    int head = kc >> 7, k = kc & 127;
    Mt[idx] = f2bf(0.5f * W[(size_t)l * 32768 + (size_t)k * 256 + head * 128 + c]);
}

// ---------------- per-layer kernels ----------------
// attention logits from fp32 x: als[n]={s_h0,s_h1}, ald[n]={d_h0,d_h1}. Wave per node, 2 cols/lane.
__global__ __launch_bounds__(256) void al_kernel(const float* __restrict__ x, const float* __restrict__ was,
                                                 const float* __restrict__ wad,
                                                 float2* __restrict__ als, float2* __restrict__ ald) {
    int n = (blockIdx.x * 256 + threadIdx.x) >> 6;
    int lane = threadIdx.x & 63;
    if (n >= N_NODES) return;
    float2 xv = *(const float2*)(x + (size_t)n * 128 + lane * 2);
    float2 ws0 = *(const float2*)(was + lane * 2);
    float2 ws1 = *(const float2*)(was + 128 + lane * 2);
    float2 wd0 = *(const float2*)(wad + lane * 2);
    float2 wd1 = *(const float2*)(wad + 128 + lane * 2);
    float s0 = xv.x * ws0.x + xv.y * ws0.y;
    float s1 = xv.x * ws1.x + xv.y * ws1.y;
    float d0 = xv.x * wd0.x + xv.y * wd0.y;
    float d1 = xv.x * wd1.x + xv.y * wd1.y;
#pragma unroll
    for (int o = 1; o < 64; o <<= 1) {
        s0 += __shfl_xor(s0, o);
        s1 += __shfl_xor(s1, o);
        d0 += __shfl_xor(d0, o);
        d1 += __shfl_xor(d1, o);
    }
    if (lane == 0) {
        als[n] = make_float2(s0, s1);
        ald[n] = make_float2(d0, d1);
    }
}

// wave per node: gather bf16 x rows (256B), 8 edge slots x 8 lanes, 16 cols/lane.
// Two per-head weighted sums share one gathered row. Output y[n][head*128+k] bf16 (alpha-normalized).
__global__ __launch_bounds__(256) void agg_kernel(const unsigned short* __restrict__ xb,
                                                  const float2* __restrict__ als, const float2* __restrict__ ald,
                                                  const int* __restrict__ ptr, const int* __restrict__ srcs,
                                                  unsigned short* __restrict__ y) {
    int n = (blockIdx.x * 256 + threadIdx.x) >> 6;
    int lane = threadIdx.x & 63;
    if (n >= N_NODES) return;
    int b = ptr[n], e = ptr[n + 1];
    float2 ad = ald[n];
    int g = lane >> 3;   // edge slot 0..7
    int gl = lane & 7;   // lane in group
    int cb = gl * 16;    // k-col base

    float a0[16], a1[16];
#pragma unroll
    for (int j = 0; j < 16; ++j) { a0[j] = 0.f; a1[j] = 0.f; }
    float d0 = 0.f, d1 = 0.f;

    int nit = (e - b + 7) >> 3;
#pragma unroll 2
    for (int it = 0; it < nit; ++it) {
        int idx = b + (it << 3) + g;
        bool act = idx < e;
        int s = srcs[act ? idx : e - 1];
        const unsigned short* hp = xb + (size_t)s * 128 + cb;
        us8 v0 = *(const us8*)hp;
        us8 v1 = *(const us8*)(hp + 8);
        float2 as2 = als[s];
        float x0 = act ? __expf(lrelu(as2.x + ad.x)) : 0.f;
        float x1 = act ? __expf(lrelu(as2.y + ad.y)) : 0.f;
        d0 += x0;
        d1 += x1;
#pragma unroll
        for (int j = 0; j < 8; ++j) {
            float f = bf2f(v0[j]);
            a0[j] += x0 * f;
            a1[j] += x1 * f;
        }
#pragma unroll
        for (int j = 0; j < 8; ++j) {
            float f = bf2f(v1[j]);
            a0[8 + j] += x0 * f;
            a1[8 + j] += x1 * f;
        }
    }

    // reduce across the 8 edge-slot groups
#pragma unroll
    for (int o = 8; o <= 32; o <<= 1) {
#pragma unroll
        for (int j = 0; j < 16; ++j) {
            a0[j] += __shfl_xor(a0[j], o);
            a1[j] += __shfl_xor(a1[j], o);
        }
        d0 += __shfl_xor(d0, o);
        d1 += __shfl_xor(d1, o);
    }

    if (g == 0) {
        float i0 = 1.0f / d0, i1 = 1.0f / d1;
        us8 o0, o1, o2, o3;
#pragma unroll
        for (int j = 0; j < 8; ++j) {
            o0[j] = f2bf(a0[j] * i0);
            o1[j] = f2bf(a0[8 + j] * i0);
            o2[j] = f2bf(a1[j] * i1);
            o3[j] = f2bf(a1[8 + j] * i1);
        }
        unsigned short* yp = y + (size_t)n * 256 + cb;
        *(us8*)yp = o0;
        *(us8*)(yp + 8) = o1;
        *(us8*)(yp + 128) = o2;
        *(us8*)(yp + 136) = o3;
    }
}

// pre = z @ M + bias : (N,256)bf16 @ (256,128) -> fp32 (N,128). 4 waves x 16 rows.
// Mt staged in LDS in two 32KB k-halves, XOR-swizzled; LDS-transpose epilogue for coalesced stores.
__global__ __launch_bounds__(256) void gemm2_kernel(const unsigned short* __restrict__ zb,
                                                    const unsigned short* __restrict__ Mt,
                                                    const float* __restrict__ bias_,
                                                    float* __restrict__ pre) {
    __shared__ unsigned short lw[128 * 128];  // 32KB
    int t = threadIdx.x;
    int w = t >> 6, l = t & 63;
    int r0 = blockIdx.x * 64 + w * 16;
    int lrow = l & 15;
    int lk = l >> 4;

    int arow = r0 + lrow;
    if (arow >= N_NODES) arow = N_NODES - 1;

    f32x4 acc[8];
#pragma unroll
    for (int i = 0; i < 8; ++i) acc[i] = (f32x4){0.f, 0.f, 0.f, 0.f};

    for (int kh = 0; kh < 2; ++kh) {
        // stage 128 cols x 128 k bf16 = 32KB, swizzled
#pragma unroll
        for (int i = 0; i < 8; ++i) {
            int chunk = t + i * 256;            // 0..2047
            int row = chunk >> 4;               // col 0..127
            int kc8 = chunk & 15;
            uint4 v = *(const uint4*)(Mt + (size_t)row * 256 + kh * 128 + kc8 * 8);
            int b = row * 256 + ((kc8 * 16) ^ ((row & 7) << 4));
            *(uint4*)((char*)lw + b) = v;
        }
        __syncthreads();
        s16x8 a[4];
#pragma unroll
        for (int ka = 0; ka < 4; ++ka)
            a[ka] = *(const s16x8*)(zb + (size_t)arow * 256 + kh * 128 + ka * 32 + lk * 8);
#pragma unroll
        for (int ct = 0; ct < 8; ++ct) {
            int row = ct * 16 + lrow;
#pragma unroll
            for (int ka = 0; ka < 4; ++ka) {
                int kb = (ka * 64 + lk * 16) ^ ((row & 7) << 4);
                s16x8 bf = *(const s16x8*)((const char*)lw + row * 256 + kb);
                acc[ct] = __builtin_amdgcn_mfma_f32_16x16x32_bf16(a[ka], bf, acc[ct], 0, 0, 0);
            }
        }
        __syncthreads();
    }

    // epilogue: transpose via LDS -> coalesced float4 stores (+bias)
    float* fl = (float*)lw;
    int wbase = w * 704;  // 4 rows x 176 words per wave
#pragma unroll
    for (int reg = 0; reg < 4; ++reg) {
#pragma unroll
        for (int ct = 0; ct < 8; ++ct)
            fl[wbase + lk * 176 + ct * 20 + lrow] = acc[ct][reg];
        __syncthreads();
        int lr2 = l >> 4;
        int cb2 = (l & 15) * 8;
        int ra = wbase + lr2 * 176 + (cb2 >> 4) * 20 + (cb2 & 15);
        f32x4 v0 = *(const f32x4*)(fl + ra);
        f32x4 v1 = *(const f32x4*)(fl + ra + 4);
        int row = r0 + lr2 * 4 + reg;
        if (row < N_NODES) {
            float4 b0 = *(const float4*)(bias_ + cb2);
            float4 b1 = *(const float4*)(bias_ + cb2 + 4);
            float4 o0 = make_float4(v0[0] + b0.x, v0[1] + b0.y, v0[2] + b0.z, v0[3] + b0.w);
            float4 o1 = make_float4(v1[0] + b1.x, v1[1] + b1.y, v1[2] + b1.z, v1[3] + b1.w);
            *(float4*)(pre + (size_t)row * 128 + cb2) = o0;
            *(float4*)(pre + (size_t)row * 128 + cb2 + 4) = o1;
        }
        __syncthreads();
    }
}

// per-channel sum and sumsq
__global__ __launch_bounds__(256) void stats_kernel(const float* __restrict__ pre, float* __restrict__ stats) {
    __shared__ float ls[256], lq[256];
    int t = threadIdx.x;
    int c = t & 127, half = t >> 7;
    float s = 0.f, q = 0.f;
    for (int r = blockIdx.x * 2 + half; r < N_NODES; r += gridDim.x * 2) {
        float v = pre[(size_t)r * 128 + c];
        s += v;
        q += v * v;
    }
    ls[t] = s;
    lq[t] = q;
    __syncthreads();
    if (half == 0) {
        atomicAdd(&stats[c], s + ls[128 + c]);
        atomicAdd(&stats[128 + c], q + lq[128 + c]);
    }
}

// BN + ELU + residual (+ optional bf16 copy for next layer's gather)
__global__ __launch_bounds__(256) void final_kernel(const float* __restrict__ pre, const float* __restrict__ res,
                                                    const float* __restrict__ gamma, const float* __restrict__ beta,
                                                    const float* __restrict__ stats, float* __restrict__ out,
                                                    unsigned short* __restrict__ xb_out) {
    const float invn = 1.0f / (float)N_NODES;
    int total = N_NODES * 32;
    for (int idx = blockIdx.x * 256 + threadIdx.x; idx < total; idx += gridDim.x * 256) {
        int c4 = (idx & 31) * 4;
        float4 v = ((const float4*)pre)[idx];
        float4 r = ((const float4*)res)[idx];
        const float* vp = (const float*)&v;
        const float* rp = (const float*)&r;
        float4 ov;
        float* op = (float*)&ov;
#pragma unroll
        for (int j = 0; j < 4; ++j) {
            int c = c4 + j;
            float mean = stats[c] * invn;
            float var = stats[128 + c] * invn - mean * mean;
            float is = rsqrtf(var + 1e-5f) * gamma[c];
            float val = (vp[j] - mean) * is + beta[c];
            val = val > 0.f ? val : (__expf(val) - 1.0f);
            op[j] = val + rp[j];
        }
        ((float4*)out)[idx] = ov;
        if (xb_out) {
            ushort4 ob;
            ob.x = f2bf(ov.x); ob.y = f2bf(ov.y); ob.z = f2bf(ov.z); ob.w = f2bf(ov.w);
            ((ushort4*)xb_out)[idx] = ob;
        }
    }
}

extern "C" void kernel_launch(void* const* d_in, const int* in_sizes, int n_in,
                              void* d_out, int out_size, void* d_ws, size_t ws_size,
                              hipStream_t stream) {
    const float* x0   = (const float*)d_in[0];
    const int* ei     = (const int*)d_in[1];
    const float* W    = (const float*)d_in[2];
    const float* asrc = (const float*)d_in[3];
    const float* adst = (const float*)d_in[4];
    const float* bias = (const float*)d_in[5];
    const float* gam  = (const float*)d_in[6];
    const float* bet  = (const float*)d_in[7];
    float* out = (float*)d_out;

    char* ws = (char*)d_ws;
    size_t off = 0;
    auto alloc = [&](size_t bytes) -> void* {
        void* p = ws + off;
        off += (bytes + 255) & ~(size_t)255;
        return p;
    };
    int* deg    = (int*)alloc((size_t)N_NODES * 4);
    int* cur    = (int*)alloc((size_t)N_NODES * 4);
    int* ptr    = (int*)alloc((size_t)(N_NODES + 1) * 4);
    int* bsum   = (int*)alloc((size_t)NB_SCAN * 4);
    int* boff   = (int*)alloc((size_t)NB_SCAN * 4);
    int* srcs   = (int*)alloc((size_t)(N_EDGES + N_NODES) * 4);
    unsigned short* xb = (unsigned short*)alloc((size_t)N_NODES * 128 * 2);  // bf16 layer input (gather table)
    unsigned short* y  = (unsigned short*)alloc((size_t)N_NODES * 256 * 2);  // bf16 z = [y_h0|y_h1]
    unsigned short* Mt = (unsigned short*)alloc((size_t)2 * 128 * 256 * 2);  // bf16 M^T per layer
    float* was  = (float*)alloc(512 * 4);
    float* wad  = (float*)alloc(512 * 4);
    float* als  = (float*)alloc((size_t)N_NODES * 2 * 4);
    float* ald  = (float*)alloc((size_t)N_NODES * 2 * 4);
    float* pre  = (float*)alloc((size_t)N_NODES * 128 * 4);
    float* x1   = (float*)alloc((size_t)N_NODES * 128 * 4);
    float* stats = (float*)alloc(512 * 4);

    hipMemsetAsync(deg, 0, (size_t)N_NODES * 4, stream);
    hipMemsetAsync(cur, 0, (size_t)N_NODES * 4, stream);
    hipMemsetAsync(stats, 0, 512 * 4, stream);

    int tot = N_EDGES + N_NODES;
    degree_kernel<<<(tot + 255) / 256, 256, 0, stream>>>(ei, deg);
    bsum_kernel<<<NB_SCAN, 256, 0, stream>>>(deg, bsum);
    bscan_kernel<<<1, 256, 0, stream>>>(bsum, boff, ptr);
    ptr_kernel<<<NB_SCAN, 256, 0, stream>>>(deg, boff, ptr);
    fill_kernel<<<(tot + 255) / 256, 256, 0, stream>>>(ei, ptr, cur, srcs);
    convert_kernel<<<2048, 256, 0, stream>>>(x0, xb);
    wa_kernel<<<2, 256, 0, stream>>>(W, asrc, adst, was, wad);
    mt_kernel<<<256, 256, 0, stream>>>(W, Mt);

    for (int l = 0; l < 2; ++l) {
        const float* xin = l ? (const float*)x1 : x0;
        float* xout = l ? out : x1;
        al_kernel<<<(N_NODES + 3) / 4, 256, 0, stream>>>(
            xin, was + l * 256, wad + l * 256, (float2*)als, (float2*)ald);
        agg_kernel<<<(N_NODES + 3) / 4, 256, 0, stream>>>(
            xb, (const float2*)als, (const float2*)ald, ptr, srcs, y);
        gemm2_kernel<<<(N_NODES + 63) / 64, 256, 0, stream>>>(
            y, Mt + (size_t)l * 32768, bias + l * 128, pre);
        stats_kernel<<<256, 256, 0, stream>>>(pre, stats + l * 256);
        final_kernel<<<2048, 256, 0, stream>>>(pre, xin, gam + l * 128, bet + l * 128, stats + l * 256,
                                               xout, l == 0 ? xb : (unsigned short*)nullptr);
    }
}

// Round 7
// 367.222 us; speedup vs baseline: 1.9279x; 1.0302x over previous
//
#include <hip/hip_runtime.h>
#include <hip/hip_bf16.h>

#define N_NODES 50000
#define N_EDGES 800000
#define NB_SCAN ((N_NODES + 255) / 256)   // 196
// C=128, H=2

typedef unsigned short us8 __attribute__((ext_vector_type(8)));
typedef short s16x8 __attribute__((ext_vector_type(8)));
typedef float f32x4 __attribute__((ext_vector_type(4)));

static __device__ __forceinline__ float lrelu(float v) { return v > 0.0f ? v : 0.2f * v; }

static __device__ __forceinline__ unsigned short f2bf(float f) {
    unsigned int u = __float_as_uint(f);
    unsigned int r = (u + 0x7FFF + ((u >> 16) & 1)) >> 16;  // RNE
    return (unsigned short)r;
}
static __device__ __forceinline__ float bf2f(unsigned short u) {
    return __uint_as_float(((unsigned int)u) << 16);
}

// ---------------- CSR build ----------------
__global__ __launch_bounds__(256) void degree_kernel(const int* __restrict__ ei, int* __restrict__ deg) {
    int i = blockIdx.x * 256 + threadIdx.x;
    int total = N_EDGES + N_NODES;
    if (i >= total) return;
    int d = (i < N_EDGES) ? ei[N_EDGES + i] : (i - N_EDGES);
    atomicAdd(&deg[d], 1);
}

__global__ __launch_bounds__(256) void bsum_kernel(const int* __restrict__ deg, int* __restrict__ bsum) {
    __shared__ int ws[4];
    int i = blockIdx.x * 256 + threadIdx.x;
    int v = (i < N_NODES) ? deg[i] : 0;
    int s = v;
#pragma unroll
    for (int o = 32; o; o >>= 1) s += __shfl_xor(s, o);
    if ((threadIdx.x & 63) == 0) ws[threadIdx.x >> 6] = s;
    __syncthreads();
    if (threadIdx.x == 0) bsum[blockIdx.x] = ws[0] + ws[1] + ws[2] + ws[3];
}

__global__ __launch_bounds__(256) void bscan_kernel(const int* __restrict__ bsum, int* __restrict__ boff,
                                                    int* __restrict__ ptr) {
    __shared__ int ps[256];
    int t = threadIdx.x;
    int v = (t < NB_SCAN) ? bsum[t] : 0;
    ps[t] = v;
    __syncthreads();
#pragma unroll
    for (int o = 1; o < 256; o <<= 1) {
        int u = (t >= o) ? ps[t - o] : 0;
        __syncthreads();
        ps[t] += u;
        __syncthreads();
    }
    if (t < NB_SCAN) boff[t] = ps[t] - v;
    if (t == NB_SCAN - 1) ptr[N_NODES] = ps[t];
}

__global__ __launch_bounds__(256) void ptr_kernel(const int* __restrict__ deg, const int* __restrict__ boff,
                                                  int* __restrict__ ptr) {
    __shared__ int ps[256];
    int t = threadIdx.x;
    int i = blockIdx.x * 256 + t;
    int v = (i < N_NODES) ? deg[i] : 0;
    ps[t] = v;
    __syncthreads();
#pragma unroll
    for (int o = 1; o < 256; o <<= 1) {
        int u = (t >= o) ? ps[t - o] : 0;
        __syncthreads();
        ps[t] += u;
        __syncthreads();
    }
    if (i < N_NODES) ptr[i] = boff[blockIdx.x] + ps[t] - v;
}

__global__ __launch_bounds__(256) void fill_kernel(const int* __restrict__ ei, const int* __restrict__ ptr,
                                                   int* __restrict__ cur, int* __restrict__ srcs) {
    int i = blockIdx.x * 256 + threadIdx.x;
    int total = N_EDGES + N_NODES;
    if (i >= total) return;
    int s, d;
    if (i < N_EDGES) { s = ei[i]; d = ei[N_EDGES + i]; }
    else { s = d = i - N_EDGES; }
    int p = atomicAdd(&cur[d], 1);
    srcs[ptr[d] + p] = s;
}

// ---------------- precompute ----------------
__global__ __launch_bounds__(256) void convert_kernel(const float* __restrict__ x, unsigned short* __restrict__ xb) {
    int total = N_NODES * 32;
    for (int i = blockIdx.x * 256 + threadIdx.x; i < total; i += gridDim.x * 256) {
        float4 v = ((const float4*)x)[i];
        ushort4 o;
        o.x = f2bf(v.x); o.y = f2bf(v.y); o.z = f2bf(v.z); o.w = f2bf(v.w);
        ((ushort4*)xb)[i] = o;
    }
}

// wa_s[l][head][k] = sum_c W[l][k][head*128+c]*as[l][head][c]; same for wa_d. blockIdx = l.
__global__ __launch_bounds__(256) void wa_kernel(const float* __restrict__ W, const float* __restrict__ as_,
                                                 const float* __restrict__ ad_, float* __restrict__ was,
                                                 float* __restrict__ wad) {
    int l = blockIdx.x;
    int t = threadIdx.x;
    int head = t >> 7, k = t & 127;
    const float* wr = W + (size_t)l * 32768 + (size_t)k * 256 + head * 128;
    const float* ar = as_ + l * 256 + head * 128;
    const float* dr = ad_ + l * 256 + head * 128;
    float s = 0.f, d = 0.f;
    for (int c = 0; c < 128; ++c) {
        float wv = wr[c];
        s += wv * ar[c];
        d += wv * dr[c];
    }
    was[l * 256 + t] = s;
    wad[l * 256 + t] = d;
}

// Mt[l][c][kc] = bf16(0.5*W[l][kc&127][(kc>>7)*128 + c])  (B^T layout, 128 cols x 256 k)
__global__ __launch_bounds__(256) void mt_kernel(const float* __restrict__ W, unsigned short* __restrict__ Mt) {
    int idx = blockIdx.x * 256 + threadIdx.x;  // 65536
    int l = idx >> 15, c = (idx >> 8) & 127, kc = idx & 255;
    int head = kc >> 7, k = kc & 127;
    Mt[idx] = f2bf(0.5f * W[(size_t)l * 32768 + (size_t)k * 256 + head * 128 + c]);
}

// ---------------- per-layer kernels ----------------
// attention logits from fp32 x: als[n]={s_h0,s_h1}, ald[n]={d_h0,d_h1}. Wave per node, 2 cols/lane.
__global__ __launch_bounds__(256) void al_kernel(const float* __restrict__ x, const float* __restrict__ was,
                                                 const float* __restrict__ wad,
                                                 float2* __restrict__ als, float2* __restrict__ ald) {
    int n = (blockIdx.x * 256 + threadIdx.x) >> 6;
    int lane = threadIdx.x & 63;
    if (n >= N_NODES) return;
    float2 xv = *(const float2*)(x + (size_t)n * 128 + lane * 2);
    float2 ws0 = *(const float2*)(was + lane * 2);
    float2 ws1 = *(const float2*)(was + 128 + lane * 2);
    float2 wd0 = *(const float2*)(wad + lane * 2);
    float2 wd1 = *(const float2*)(wad + 128 + lane * 2);
    float s0 = xv.x * ws0.x + xv.y * ws0.y;
    float s1 = xv.x * ws1.x + xv.y * ws1.y;
    float d0 = xv.x * wd0.x + xv.y * wd0.y;
    float d1 = xv.x * wd1.x + xv.y * wd1.y;
#pragma unroll
    for (int o = 1; o < 64; o <<= 1) {
        s0 += __shfl_xor(s0, o);
        s1 += __shfl_xor(s1, o);
        d0 += __shfl_xor(d0, o);
        d1 += __shfl_xor(d1, o);
    }
    if (lane == 0) {
        als[n] = make_float2(s0, s1);
        ald[n] = make_float2(d0, d1);
    }
}

// per-edge unnormalized weights + per-node denominators. Wave per node, lane-parallel edges.
__global__ __launch_bounds__(256) void alpha_kernel(const float2* __restrict__ als, const float2* __restrict__ ald,
                                                    const int* __restrict__ ptr, const int* __restrict__ srcs,
                                                    float2* __restrict__ alpha, float2* __restrict__ denom) {
    int n = (blockIdx.x * 256 + threadIdx.x) >> 6;
    int lane = threadIdx.x & 63;
    if (n >= N_NODES) return;
    int b = ptr[n], e = ptr[n + 1];
    float2 ad = ald[n];
    float s0 = 0.f, s1 = 0.f;
    for (int i = b + lane; i < e; i += 64) {
        float2 as2 = als[srcs[i]];
        float w0 = __expf(lrelu(as2.x + ad.x));
        float w1 = __expf(lrelu(as2.y + ad.y));
        alpha[i] = make_float2(w0, w1);
        s0 += w0;
        s1 += w1;
    }
#pragma unroll
    for (int o = 32; o; o >>= 1) {
        s0 += __shfl_xor(s0, o);
        s1 += __shfl_xor(s1, o);
    }
    if (lane == 0) denom[n] = make_float2(s0, s1);
}

// 16-lane group per node (4 nodes/wave); lane covers 8 bf16 cols (16B load = full 256B row per group).
// Inner loop: broadcast alpha[i] + one us8 x-row load + 16 FMA. No cross-lane reduction at all.
__global__ __launch_bounds__(256) void agg_kernel(const unsigned short* __restrict__ xb,
                                                  const float2* __restrict__ alpha,
                                                  const float2* __restrict__ denom,
                                                  const int* __restrict__ ptr, const int* __restrict__ srcs,
                                                  unsigned short* __restrict__ y) {
    int tid = blockIdx.x * 256 + threadIdx.x;
    int n = tid >> 4;
    int gl = tid & 15;
    if (n >= N_NODES) return;
    int b = ptr[n], e = ptr[n + 1];
    int cb = gl * 8;   // col base

    float a0[8], a1[8];
#pragma unroll
    for (int j = 0; j < 8; ++j) { a0[j] = 0.f; a1[j] = 0.f; }

    for (int i = b; i < e; ++i) {
        int s = srcs[i];
        float2 al2 = alpha[i];
        us8 v = *(const us8*)(xb + (size_t)s * 128 + cb);
#pragma unroll
        for (int j = 0; j < 8; ++j) {
            float f = bf2f(v[j]);
            a0[j] += al2.x * f;
            a1[j] += al2.y * f;
        }
    }

    float2 dn = denom[n];
    float i0 = 1.0f / dn.x, i1 = 1.0f / dn.y;
    us8 o0, o1;
#pragma unroll
    for (int j = 0; j < 8; ++j) {
        o0[j] = f2bf(a0[j] * i0);
        o1[j] = f2bf(a1[j] * i1);
    }
    unsigned short* yp = y + (size_t)n * 256 + cb;
    *(us8*)yp = o0;
    *(us8*)(yp + 128) = o1;
}

// pre = z @ M + bias : (N,256)bf16 @ (256,128) -> fp32 (N,128). 4 waves x 16 rows.
__global__ __launch_bounds__(256) void gemm2_kernel(const unsigned short* __restrict__ zb,
                                                    const unsigned short* __restrict__ Mt,
                                                    const float* __restrict__ bias_,
                                                    float* __restrict__ pre) {
    __shared__ unsigned short lw[128 * 128];  // 32KB
    int t = threadIdx.x;
    int w = t >> 6, l = t & 63;
    int r0 = blockIdx.x * 64 + w * 16;
    int lrow = l & 15;
    int lk = l >> 4;

    int arow = r0 + lrow;
    if (arow >= N_NODES) arow = N_NODES - 1;

    f32x4 acc[8];
#pragma unroll
    for (int i = 0; i < 8; ++i) acc[i] = (f32x4){0.f, 0.f, 0.f, 0.f};

    for (int kh = 0; kh < 2; ++kh) {
#pragma unroll
        for (int i = 0; i < 8; ++i) {
            int chunk = t + i * 256;            // 0..2047
            int row = chunk >> 4;               // col 0..127
            int kc8 = chunk & 15;
            uint4 v = *(const uint4*)(Mt + (size_t)row * 256 + kh * 128 + kc8 * 8);
            int b = row * 256 + ((kc8 * 16) ^ ((row & 7) << 4));
            *(uint4*)((char*)lw + b) = v;
        }
        __syncthreads();
        s16x8 a[4];
#pragma unroll
        for (int ka = 0; ka < 4; ++ka)
            a[ka] = *(const s16x8*)(zb + (size_t)arow * 256 + kh * 128 + ka * 32 + lk * 8);
#pragma unroll
        for (int ct = 0; ct < 8; ++ct) {
            int row = ct * 16 + lrow;
#pragma unroll
            for (int ka = 0; ka < 4; ++ka) {
                int kb = (ka * 64 + lk * 16) ^ ((row & 7) << 4);
                s16x8 bf = *(const s16x8*)((const char*)lw + row * 256 + kb);
                acc[ct] = __builtin_amdgcn_mfma_f32_16x16x32_bf16(a[ka], bf, acc[ct], 0, 0, 0);
            }
        }
        __syncthreads();
    }

    // epilogue: transpose via LDS -> coalesced float4 stores (+bias)
    float* fl = (float*)lw;
    int wbase = w * 704;  // 4 rows x 176 words per wave
#pragma unroll
    for (int reg = 0; reg < 4; ++reg) {
#pragma unroll
        for (int ct = 0; ct < 8; ++ct)
            fl[wbase + lk * 176 + ct * 20 + lrow] = acc[ct][reg];
        __syncthreads();
        int lr2 = l >> 4;
        int cb2 = (l & 15) * 8;
        int ra = wbase + lr2 * 176 + (cb2 >> 4) * 20 + (cb2 & 15);
        f32x4 v0 = *(const f32x4*)(fl + ra);
        f32x4 v1 = *(const f32x4*)(fl + ra + 4);
        int row = r0 + lr2 * 4 + reg;
        if (row < N_NODES) {
            float4 b0 = *(const float4*)(bias_ + cb2);
            float4 b1 = *(const float4*)(bias_ + cb2 + 4);
            float4 o0 = make_float4(v0[0] + b0.x, v0[1] + b0.y, v0[2] + b0.z, v0[3] + b0.w);
            float4 o1 = make_float4(v1[0] + b1.x, v1[1] + b1.y, v1[2] + b1.z, v1[3] + b1.w);
            *(float4*)(pre + (size_t)row * 128 + cb2) = o0;
            *(float4*)(pre + (size_t)row * 128 + cb2 + 4) = o1;
        }
        __syncthreads();
    }
}

// per-channel sum and sumsq
__global__ __launch_bounds__(256) void stats_kernel(const float* __restrict__ pre, float* __restrict__ stats) {
    __shared__ float ls[256], lq[256];
    int t = threadIdx.x;
    int c = t & 127, half = t >> 7;
    float s = 0.f, q = 0.f;
    for (int r = blockIdx.x * 2 + half; r < N_NODES; r += gridDim.x * 2) {
        float v = pre[(size_t)r * 128 + c];
        s += v;
        q += v * v;
    }
    ls[t] = s;
    lq[t] = q;
    __syncthreads();
    if (half == 0) {
        atomicAdd(&stats[c], s + ls[128 + c]);
        atomicAdd(&stats[128 + c], q + lq[128 + c]);
    }
}

// BN + ELU + residual (+ optional bf16 copy for next layer's gather)
__global__ __launch_bounds__(256) void final_kernel(const float* __restrict__ pre, const float* __restrict__ res,
                                                    const float* __restrict__ gamma, const float* __restrict__ beta,
                                                    const float* __restrict__ stats, float* __restrict__ out,
                                                    unsigned short* __restrict__ xb_out) {
    const float invn = 1.0f / (float)N_NODES;
    int total = N_NODES * 32;
    for (int idx = blockIdx.x * 256 + threadIdx.x; idx < total; idx += gridDim.x * 256) {
        int c4 = (idx & 31) * 4;
        float4 v = ((const float4*)pre)[idx];
        float4 r = ((const float4*)res)[idx];
        const float* vp = (const float*)&v;
        const float* rp = (const float*)&r;
        float4 ov;
        float* op = (float*)&ov;
#pragma unroll
        for (int j = 0; j < 4; ++j) {
            int c = c4 + j;
            float mean = stats[c] * invn;
            float var = stats[128 + c] * invn - mean * mean;
            float is = rsqrtf(var + 1e-5f) * gamma[c];
            float val = (vp[j] - mean) * is + beta[c];
            val = val > 0.f ? val : (__expf(val) - 1.0f);
            op[j] = val + rp[j];
        }
        ((float4*)out)[idx] = ov;
        if (xb_out) {
            ushort4 ob;
            ob.x = f2bf(ov.x); ob.y = f2bf(ov.y); ob.z = f2bf(ov.z); ob.w = f2bf(ov.w);
            ((ushort4*)xb_out)[idx] = ob;
        }
    }
}

extern "C" void kernel_launch(void* const* d_in, const int* in_sizes, int n_in,
                              void* d_out, int out_size, void* d_ws, size_t ws_size,
                              hipStream_t stream) {
    const float* x0   = (const float*)d_in[0];
    const int* ei     = (const int*)d_in[1];
    const float* W    = (const float*)d_in[2];
    const float* asrc = (const float*)d_in[3];
    const float* adst = (const float*)d_in[4];
    const float* bias = (const float*)d_in[5];
    const float* gam  = (const float*)d_in[6];
    const float* bet  = (const float*)d_in[7];
    float* out = (float*)d_out;

    char* ws = (char*)d_ws;
    size_t off = 0;
    auto alloc = [&](size_t bytes) -> void* {
        void* p = ws + off;
        off += (bytes + 255) & ~(size_t)255;
        return p;
    };
    int* deg    = (int*)alloc((size_t)N_NODES * 4);
    int* cur    = (int*)alloc((size_t)N_NODES * 4);
    int* ptr    = (int*)alloc((size_t)(N_NODES + 1) * 4);
    int* bsum   = (int*)alloc((size_t)NB_SCAN * 4);
    int* boff   = (int*)alloc((size_t)NB_SCAN * 4);
    int* srcs   = (int*)alloc((size_t)(N_EDGES + N_NODES) * 4);
    unsigned short* xb = (unsigned short*)alloc((size_t)N_NODES * 128 * 2);  // bf16 layer input (gather table)
    unsigned short* y  = (unsigned short*)alloc((size_t)N_NODES * 256 * 2);  // bf16 z = [y_h0|y_h1]
    unsigned short* Mt = (unsigned short*)alloc((size_t)2 * 128 * 256 * 2);  // bf16 M^T per layer
    float* was  = (float*)alloc(512 * 4);
    float* wad  = (float*)alloc(512 * 4);
    float* als  = (float*)alloc((size_t)N_NODES * 2 * 4);
    float* ald  = (float*)alloc((size_t)N_NODES * 2 * 4);
    float* alpha = (float*)alloc((size_t)(N_EDGES + N_NODES) * 2 * 4);
    float* denom = (float*)alloc((size_t)N_NODES * 2 * 4);
    float* pre  = (float*)alloc((size_t)N_NODES * 128 * 4);
    float* x1   = (float*)alloc((size_t)N_NODES * 128 * 4);
    float* stats = (float*)alloc(512 * 4);

    hipMemsetAsync(deg, 0, (size_t)N_NODES * 4, stream);
    hipMemsetAsync(cur, 0, (size_t)N_NODES * 4, stream);
    hipMemsetAsync(stats, 0, 512 * 4, stream);

    int tot = N_EDGES + N_NODES;
    degree_kernel<<<(tot + 255) / 256, 256, 0, stream>>>(ei, deg);
    bsum_kernel<<<NB_SCAN, 256, 0, stream>>>(deg, bsum);
    bscan_kernel<<<1, 256, 0, stream>>>(bsum, boff, ptr);
    ptr_kernel<<<NB_SCAN, 256, 0, stream>>>(deg, boff, ptr);
    fill_kernel<<<(tot + 255) / 256, 256, 0, stream>>>(ei, ptr, cur, srcs);
    convert_kernel<<<2048, 256, 0, stream>>>(x0, xb);
    wa_kernel<<<2, 256, 0, stream>>>(W, asrc, adst, was, wad);
    mt_kernel<<<256, 256, 0, stream>>>(W, Mt);

    for (int l = 0; l < 2; ++l) {
        const float* xin = l ? (const float*)x1 : x0;
        float* xout = l ? out : x1;
        al_kernel<<<(N_NODES + 3) / 4, 256, 0, stream>>>(
            xin, was + l * 256, wad + l * 256, (float2*)als, (float2*)ald);
        alpha_kernel<<<(N_NODES + 3) / 4, 256, 0, stream>>>(
            (const float2*)als, (const float2*)ald, ptr, srcs, (float2*)alpha, (float2*)denom);
        agg_kernel<<<(N_NODES * 16 + 255) / 256, 256, 0, stream>>>(
            xb, (const float2*)alpha, (const float2*)denom, ptr, srcs, y);
        gemm2_kernel<<<(N_NODES + 63) / 64, 256, 0, stream>>>(
            y, Mt + (size_t)l * 32768, bias + l * 128, pre);
        stats_kernel<<<256, 256, 0, stream>>>(pre, stats + l * 256);
        final_kernel<<<2048, 256, 0, stream>>>(pre, xin, gam + l * 128, bet + l * 128, stats + l * 256,
                                               xout, l == 0 ? xb : (unsigned short*)nullptr);
    }
}

// Round 8
// 360.845 us; speedup vs baseline: 1.9620x; 1.0177x over previous
//
#include <hip/hip_runtime.h>
#include <hip/hip_bf16.h>

#define N_NODES 50000
#define N_EDGES 800000
#define TOT_E (N_EDGES + N_NODES)
#define NB_SCAN ((N_NODES + 255) / 256)   // 196
#define NPART 8
#define PSIZE ((N_NODES + NPART - 1) / NPART)   // 6250
#define NCHUNK 128
#define CE ((TOT_E + NCHUNK - 1) / NCHUNK)      // 6641
// C=128, H=2

typedef unsigned short us8 __attribute__((ext_vector_type(8)));
typedef short s16x8 __attribute__((ext_vector_type(8)));
typedef float f32x4 __attribute__((ext_vector_type(4)));

static __device__ __forceinline__ float lrelu(float v) { return v > 0.0f ? v : 0.2f * v; }

static __device__ __forceinline__ unsigned short f2bf(float f) {
    unsigned int u = __float_as_uint(f);
    unsigned int r = (u + 0x7FFF + ((u >> 16) & 1)) >> 16;  // RNE
    return (unsigned short)r;
}
static __device__ __forceinline__ float bf2f(unsigned short u) {
    return __uint_as_float(((unsigned int)u) << 16);
}

// ---------------- CSR build (XCD-partitioned) ----------------
// block j: edge chunk j>>3, keeps only dst in partition j&7. With round-robin
// blockIdx->XCD dispatch each partition's deg/cur/srcs range is single-XCD-owned
// (correctness does not depend on the mapping; only locality does).
__global__ __launch_bounds__(256) void degree_kernel(const int* __restrict__ ei, int* __restrict__ deg) {
    int j = blockIdx.x;
    int p = j & (NPART - 1);
    int c = j >> 3;
    int lo = c * CE;
    int hi = lo + CE < TOT_E ? lo + CE : TOT_E;
    int plo = p * PSIZE, phi = plo + PSIZE;
    for (int i = lo + threadIdx.x; i < hi; i += 256) {
        int d = (i < N_EDGES) ? ei[N_EDGES + i] : (i - N_EDGES);
        if (d >= plo && d < phi) atomicAdd(&deg[d], 1);
    }
}

__global__ __launch_bounds__(256) void bsum_kernel(const int* __restrict__ deg, int* __restrict__ bsum) {
    __shared__ int ws[4];
    int i = blockIdx.x * 256 + threadIdx.x;
    int v = (i < N_NODES) ? deg[i] : 0;
    int s = v;
#pragma unroll
    for (int o = 32; o; o >>= 1) s += __shfl_xor(s, o);
    if ((threadIdx.x & 63) == 0) ws[threadIdx.x >> 6] = s;
    __syncthreads();
    if (threadIdx.x == 0) bsum[blockIdx.x] = ws[0] + ws[1] + ws[2] + ws[3];
}

__global__ __launch_bounds__(256) void bscan_kernel(const int* __restrict__ bsum, int* __restrict__ boff,
                                                    int* __restrict__ ptr) {
    __shared__ int ps[256];
    int t = threadIdx.x;
    int v = (t < NB_SCAN) ? bsum[t] : 0;
    ps[t] = v;
    __syncthreads();
#pragma unroll
    for (int o = 1; o < 256; o <<= 1) {
        int u = (t >= o) ? ps[t - o] : 0;
        __syncthreads();
        ps[t] += u;
        __syncthreads();
    }
    if (t < NB_SCAN) boff[t] = ps[t] - v;
    if (t == NB_SCAN - 1) ptr[N_NODES] = ps[t];
}

// in-block scan + block offset -> ptr; also initializes cur = ptr (fill's atomic counters)
__global__ __launch_bounds__(256) void ptr_kernel(const int* __restrict__ deg, const int* __restrict__ boff,
                                                  int* __restrict__ ptr, int* __restrict__ cur) {
    __shared__ int ps[256];
    int t = threadIdx.x;
    int i = blockIdx.x * 256 + t;
    int v = (i < N_NODES) ? deg[i] : 0;
    ps[t] = v;
    __syncthreads();
#pragma unroll
    for (int o = 1; o < 256; o <<= 1) {
        int u = (t >= o) ? ps[t - o] : 0;
        __syncthreads();
        ps[t] += u;
        __syncthreads();
    }
    if (i < N_NODES) {
        int val = boff[blockIdx.x] + ps[t] - v;
        ptr[i] = val;
        cur[i] = val;
    }
}

__global__ __launch_bounds__(256) void fill_kernel(const int* __restrict__ ei, int* __restrict__ cur,
                                                   unsigned short* __restrict__ srcs) {
    int j = blockIdx.x;
    int p = j & (NPART - 1);
    int c = j >> 3;
    int lo = c * CE;
    int hi = lo + CE < TOT_E ? lo + CE : TOT_E;
    int plo = p * PSIZE, phi = plo + PSIZE;
    for (int i = lo + threadIdx.x; i < hi; i += 256) {
        int s, d;
        if (i < N_EDGES) { s = ei[i]; d = ei[N_EDGES + i]; }
        else { s = d = i - N_EDGES; }
        if (d >= plo && d < phi) {
            int slot = atomicAdd(&cur[d], 1);
            srcs[slot] = (unsigned short)s;
        }
    }
}

// ---------------- precompute ----------------
__global__ __launch_bounds__(256) void convert_kernel(const float* __restrict__ x, unsigned short* __restrict__ xb) {
    int total = N_NODES * 32;
    for (int i = blockIdx.x * 256 + threadIdx.x; i < total; i += gridDim.x * 256) {
        float4 v = ((const float4*)x)[i];
        ushort4 o;
        o.x = f2bf(v.x); o.y = f2bf(v.y); o.z = f2bf(v.z); o.w = f2bf(v.w);
        ((ushort4*)xb)[i] = o;
    }
}

// wa_s[l][head][k] = sum_c W[l][k][head*128+c]*as[l][head][c]; same for wa_d. blockIdx = l.
__global__ __launch_bounds__(256) void wa_kernel(const float* __restrict__ W, const float* __restrict__ as_,
                                                 const float* __restrict__ ad_, float* __restrict__ was,
                                                 float* __restrict__ wad) {
    int l = blockIdx.x;
    int t = threadIdx.x;
    int head = t >> 7, k = t & 127;
    const float* wr = W + (size_t)l * 32768 + (size_t)k * 256 + head * 128;
    const float* ar = as_ + l * 256 + head * 128;
    const float* dr = ad_ + l * 256 + head * 128;
    float s = 0.f, d = 0.f;
    for (int c = 0; c < 128; ++c) {
        float wv = wr[c];
        s += wv * ar[c];
        d += wv * dr[c];
    }
    was[l * 256 + t] = s;
    wad[l * 256 + t] = d;
}

// Mt[l][c][kc] = bf16(0.5*W[l][kc&127][(kc>>7)*128 + c])  (B^T layout, 128 cols x 256 k)
__global__ __launch_bounds__(256) void mt_kernel(const float* __restrict__ W, unsigned short* __restrict__ Mt) {
    int idx = blockIdx.x * 256 + threadIdx.x;  // 65536
    int l = idx >> 15, c = (idx >> 8) & 127, kc = idx & 255;
    int head = kc >> 7, k = kc & 127;
    Mt[idx] = f2bf(0.5f * W[(size_t)l * 32768 + (size_t)k * 256 + head * 128 + c]);
}

// ---------------- per-layer kernels ----------------
// attention logits from fp32 x: als[n]={s_h0,s_h1}, ald[n]={d_h0,d_h1}. Wave per node, 2 cols/lane.
__global__ __launch_bounds__(256) void al_kernel(const float* __restrict__ x, const float* __restrict__ was,
                                                 const float* __restrict__ wad,
                                                 float2* __restrict__ als, float2* __restrict__ ald) {
    int n = (blockIdx.x * 256 + threadIdx.x) >> 6;
    int lane = threadIdx.x & 63;
    if (n >= N_NODES) return;
    float2 xv = *(const float2*)(x + (size_t)n * 128 + lane * 2);
    float2 ws0 = *(const float2*)(was + lane * 2);
    float2 ws1 = *(const float2*)(was + 128 + lane * 2);
    float2 wd0 = *(const float2*)(wad + lane * 2);
    float2 wd1 = *(const float2*)(wad + 128 + lane * 2);
    float s0 = xv.x * ws0.x + xv.y * ws0.y;
    float s1 = xv.x * ws1.x + xv.y * ws1.y;
    float d0 = xv.x * wd0.x + xv.y * wd0.y;
    float d1 = xv.x * wd1.x + xv.y * wd1.y;
#pragma unroll
    for (int o = 1; o < 64; o <<= 1) {
        s0 += __shfl_xor(s0, o);
        s1 += __shfl_xor(s1, o);
        d0 += __shfl_xor(d0, o);
        d1 += __shfl_xor(d1, o);
    }
    if (lane == 0) {
        als[n] = make_float2(s0, s1);
        ald[n] = make_float2(d0, d1);
    }
}

// per-edge unnormalized weights + per-node denominators. Wave per node, lane-parallel edges.
__global__ __launch_bounds__(256) void alpha_kernel(const float2* __restrict__ als, const float2* __restrict__ ald,
                                                    const int* __restrict__ ptr,
                                                    const unsigned short* __restrict__ srcs,
                                                    float2* __restrict__ alpha, float2* __restrict__ denom) {
    int n = (blockIdx.x * 256 + threadIdx.x) >> 6;
    int lane = threadIdx.x & 63;
    if (n >= N_NODES) return;
    int b = ptr[n], e = ptr[n + 1];
    float2 ad = ald[n];
    float s0 = 0.f, s1 = 0.f;
    for (int i = b + lane; i < e; i += 64) {
        float2 as2 = als[srcs[i]];
        float w0 = __expf(lrelu(as2.x + ad.x));
        float w1 = __expf(lrelu(as2.y + ad.y));
        alpha[i] = make_float2(w0, w1);
        s0 += w0;
        s1 += w1;
    }
#pragma unroll
    for (int o = 32; o; o >>= 1) {
        s0 += __shfl_xor(s0, o);
        s1 += __shfl_xor(s1, o);
    }
    if (lane == 0) denom[n] = make_float2(s0, s1);
}

// 16-lane group per node (4 nodes/wave); lane covers 8 bf16 cols (16B load = full 256B row per group).
__global__ __launch_bounds__(256) void agg_kernel(const unsigned short* __restrict__ xb,
                                                  const float2* __restrict__ alpha,
                                                  const float2* __restrict__ denom,
                                                  const int* __restrict__ ptr,
                                                  const unsigned short* __restrict__ srcs,
                                                  unsigned short* __restrict__ y) {
    int tid = blockIdx.x * 256 + threadIdx.x;
    int n = tid >> 4;
    int gl = tid & 15;
    if (n >= N_NODES) return;
    int b = ptr[n], e = ptr[n + 1];
    int cb = gl * 8;   // col base

    float a0[8], a1[8];
#pragma unroll
    for (int j = 0; j < 8; ++j) { a0[j] = 0.f; a1[j] = 0.f; }

    for (int i = b; i < e; ++i) {
        int s = srcs[i];
        float2 al2 = alpha[i];
        us8 v = *(const us8*)(xb + (size_t)s * 128 + cb);
#pragma unroll
        for (int j = 0; j < 8; ++j) {
            float f = bf2f(v[j]);
            a0[j] += al2.x * f;
            a1[j] += al2.y * f;
        }
    }

    float2 dn = denom[n];
    float i0 = 1.0f / dn.x, i1 = 1.0f / dn.y;
    us8 o0, o1;
#pragma unroll
    for (int j = 0; j < 8; ++j) {
        o0[j] = f2bf(a0[j] * i0);
        o1[j] = f2bf(a1[j] * i1);
    }
    unsigned short* yp = y + (size_t)n * 256 + cb;
    *(us8*)yp = o0;
    *(us8*)(yp + 128) = o1;
}

// pre = z @ M + bias : (N,256)bf16 @ (256,128) -> fp32 (N,128). 4 waves x 16 rows.
__global__ __launch_bounds__(256) void gemm2_kernel(const unsigned short* __restrict__ zb,
                                                    const unsigned short* __restrict__ Mt,
                                                    const float* __restrict__ bias_,
                                                    float* __restrict__ pre) {
    __shared__ unsigned short lw[128 * 128];  // 32KB
    int t = threadIdx.x;
    int w = t >> 6, l = t & 63;
    int r0 = blockIdx.x * 64 + w * 16;
    int lrow = l & 15;
    int lk = l >> 4;

    int arow = r0 + lrow;
    if (arow >= N_NODES) arow = N_NODES - 1;

    f32x4 acc[8];
#pragma unroll
    for (int i = 0; i < 8; ++i) acc[i] = (f32x4){0.f, 0.f, 0.f, 0.f};

    for (int kh = 0; kh < 2; ++kh) {
#pragma unroll
        for (int i = 0; i < 8; ++i) {
            int chunk = t + i * 256;            // 0..2047
            int row = chunk >> 4;               // col 0..127
            int kc8 = chunk & 15;
            uint4 v = *(const uint4*)(Mt + (size_t)row * 256 + kh * 128 + kc8 * 8);
            int b = row * 256 + ((kc8 * 16) ^ ((row & 7) << 4));
            *(uint4*)((char*)lw + b) = v;
        }
        __syncthreads();
        s16x8 a[4];
#pragma unroll
        for (int ka = 0; ka < 4; ++ka)
            a[ka] = *(const s16x8*)(zb + (size_t)arow * 256 + kh * 128 + ka * 32 + lk * 8);
#pragma unroll
        for (int ct = 0; ct < 8; ++ct) {
            int row = ct * 16 + lrow;
#pragma unroll
            for (int ka = 0; ka < 4; ++ka) {
                int kb = (ka * 64 + lk * 16) ^ ((row & 7) << 4);
                s16x8 bf = *(const s16x8*)((const char*)lw + row * 256 + kb);
                acc[ct] = __builtin_amdgcn_mfma_f32_16x16x32_bf16(a[ka], bf, acc[ct], 0, 0, 0);
            }
        }
        __syncthreads();
    }

    // epilogue: transpose via LDS -> coalesced float4 stores (+bias)
    float* fl = (float*)lw;
    int wbase = w * 704;  // 4 rows x 176 words per wave
#pragma unroll
    for (int reg = 0; reg < 4; ++reg) {
#pragma unroll
        for (int ct = 0; ct < 8; ++ct)
            fl[wbase + lk * 176 + ct * 20 + lrow] = acc[ct][reg];
        __syncthreads();
        int lr2 = l >> 4;
        int cb2 = (l & 15) * 8;
        int ra = wbase + lr2 * 176 + (cb2 >> 4) * 20 + (cb2 & 15);
        f32x4 v0 = *(const f32x4*)(fl + ra);
        f32x4 v1 = *(const f32x4*)(fl + ra + 4);
        int row = r0 + lr2 * 4 + reg;
        if (row < N_NODES) {
            float4 b0 = *(const float4*)(bias_ + cb2);
            float4 b1 = *(const float4*)(bias_ + cb2 + 4);
            float4 o0 = make_float4(v0[0] + b0.x, v0[1] + b0.y, v0[2] + b0.z, v0[3] + b0.w);
            float4 o1 = make_float4(v1[0] + b1.x, v1[1] + b1.y, v1[2] + b1.z, v1[3] + b1.w);
            *(float4*)(pre + (size_t)row * 128 + cb2) = o0;
            *(float4*)(pre + (size_t)row * 128 + cb2 + 4) = o1;
        }
        __syncthreads();
    }
}

// per-channel sum and sumsq
__global__ __launch_bounds__(256) void stats_kernel(const float* __restrict__ pre, float* __restrict__ stats) {
    __shared__ float ls[256], lq[256];
    int t = threadIdx.x;
    int c = t & 127, half = t >> 7;
    float s = 0.f, q = 0.f;
    for (int r = blockIdx.x * 2 + half; r < N_NODES; r += gridDim.x * 2) {
        float v = pre[(size_t)r * 128 + c];
        s += v;
        q += v * v;
    }
    ls[t] = s;
    lq[t] = q;
    __syncthreads();
    if (half == 0) {
        atomicAdd(&stats[c], s + ls[128 + c]);
        atomicAdd(&stats[128 + c], q + lq[128 + c]);
    }
}

// BN + ELU + residual (+ optional bf16 copy for next layer's gather)
__global__ __launch_bounds__(256) void final_kernel(const float* __restrict__ pre, const float* __restrict__ res,
                                                    const float* __restrict__ gamma, const float* __restrict__ beta,
                                                    const float* __restrict__ stats, float* __restrict__ out,
                                                    unsigned short* __restrict__ xb_out) {
    const float invn = 1.0f / (float)N_NODES;
    int total = N_NODES * 32;
    for (int idx = blockIdx.x * 256 + threadIdx.x; idx < total; idx += gridDim.x * 256) {
        int c4 = (idx & 31) * 4;
        float4 v = ((const float4*)pre)[idx];
        float4 r = ((const float4*)res)[idx];
        const float* vp = (const float*)&v;
        const float* rp = (const float*)&r;
        float4 ov;
        float* op = (float*)&ov;
#pragma unroll
        for (int j = 0; j < 4; ++j) {
            int c = c4 + j;
            float mean = stats[c] * invn;
            float var = stats[128 + c] * invn - mean * mean;
            float is = rsqrtf(var + 1e-5f) * gamma[c];
            float val = (vp[j] - mean) * is + beta[c];
            val = val > 0.f ? val : (__expf(val) - 1.0f);
            op[j] = val + rp[j];
        }
        ((float4*)out)[idx] = ov;
        if (xb_out) {
            ushort4 ob;
            ob.x = f2bf(ov.x); ob.y = f2bf(ov.y); ob.z = f2bf(ov.z); ob.w = f2bf(ov.w);
            ((ushort4*)xb_out)[idx] = ob;
        }
    }
}

extern "C" void kernel_launch(void* const* d_in, const int* in_sizes, int n_in,
                              void* d_out, int out_size, void* d_ws, size_t ws_size,
                              hipStream_t stream) {
    const float* x0   = (const float*)d_in[0];
    const int* ei     = (const int*)d_in[1];
    const float* W    = (const float*)d_in[2];
    const float* asrc = (const float*)d_in[3];
    const float* adst = (const float*)d_in[4];
    const float* bias = (const float*)d_in[5];
    const float* gam  = (const float*)d_in[6];
    const float* bet  = (const float*)d_in[7];
    float* out = (float*)d_out;

    char* ws = (char*)d_ws;
    size_t off = 0;
    auto alloc = [&](size_t bytes) -> void* {
        void* p = ws + off;
        off += (bytes + 255) & ~(size_t)255;
        return p;
    };
    int* deg    = (int*)alloc((size_t)N_NODES * 4);
    int* cur    = (int*)alloc((size_t)N_NODES * 4);
    int* ptr    = (int*)alloc((size_t)(N_NODES + 1) * 4);
    int* bsum   = (int*)alloc((size_t)NB_SCAN * 4);
    int* boff   = (int*)alloc((size_t)NB_SCAN * 4);
    unsigned short* srcs = (unsigned short*)alloc((size_t)TOT_E * 2);
    unsigned short* xb = (unsigned short*)alloc((size_t)N_NODES * 128 * 2);  // bf16 layer input (gather table)
    unsigned short* y  = (unsigned short*)alloc((size_t)N_NODES * 256 * 2);  // bf16 z = [y_h0|y_h1]
    unsigned short* Mt = (unsigned short*)alloc((size_t)2 * 128 * 256 * 2);  // bf16 M^T per layer
    float* was  = (float*)alloc(512 * 4);
    float* wad  = (float*)alloc(512 * 4);
    float* als  = (float*)alloc((size_t)N_NODES * 2 * 4);
    float* ald  = (float*)alloc((size_t)N_NODES * 2 * 4);
    float* alpha = (float*)alloc((size_t)TOT_E * 2 * 4);
    float* denom = (float*)alloc((size_t)N_NODES * 2 * 4);
    float* pre  = (float*)alloc((size_t)N_NODES * 128 * 4);
    float* x1   = (float*)alloc((size_t)N_NODES * 128 * 4);
    float* stats = (float*)alloc(512 * 4);

    hipMemsetAsync(deg, 0, (size_t)N_NODES * 4, stream);
    hipMemsetAsync(stats, 0, 512 * 4, stream);

    degree_kernel<<<NCHUNK * NPART, 256, 0, stream>>>(ei, deg);
    bsum_kernel<<<NB_SCAN, 256, 0, stream>>>(deg, bsum);
    bscan_kernel<<<1, 256, 0, stream>>>(bsum, boff, ptr);
    ptr_kernel<<<NB_SCAN, 256, 0, stream>>>(deg, boff, ptr, cur);
    fill_kernel<<<NCHUNK * NPART, 256, 0, stream>>>(ei, cur, srcs);
    convert_kernel<<<2048, 256, 0, stream>>>(x0, xb);
    wa_kernel<<<2, 256, 0, stream>>>(W, asrc, adst, was, wad);
    mt_kernel<<<256, 256, 0, stream>>>(W, Mt);

    for (int l = 0; l < 2; ++l) {
        const float* xin = l ? (const float*)x1 : x0;
        float* xout = l ? out : x1;
        al_kernel<<<(N_NODES + 3) / 4, 256, 0, stream>>>(
            xin, was + l * 256, wad + l * 256, (float2*)als, (float2*)ald);
        alpha_kernel<<<(N_NODES + 3) / 4, 256, 0, stream>>>(
            (const float2*)als, (const float2*)ald, ptr, srcs, (float2*)alpha, (float2*)denom);
        agg_kernel<<<(N_NODES * 16 + 255) / 256, 256, 0, stream>>>(
            xb, (const float2*)alpha, (const float2*)denom, ptr, srcs, y);
        gemm2_kernel<<<(N_NODES + 63) / 64, 256, 0, stream>>>(
            y, Mt + (size_t)l * 32768, bias + l * 128, pre);
        stats_kernel<<<256, 256, 0, stream>>>(pre, stats + l * 256);
        final_kernel<<<2048, 256, 0, stream>>>(pre, xin, gam + l * 128, bet + l * 128, stats + l * 256,
                                               xout, l == 0 ? xb : (unsigned short*)nullptr);
    }
}

// Round 9
// 279.115 us; speedup vs baseline: 2.5365x; 1.2928x over previous
//
#include <hip/hip_runtime.h>
#include <hip/hip_bf16.h>

#define N_NODES 50000
#define N_EDGES 800000
#define TOT_E (N_EDGES + N_NODES)
#define PS 256                              // nodes per partition
#define NP ((N_NODES + PS - 1) / PS)        // 196 partitions
#define BCAP 6000                           // bucket capacity (avg 4352, sd ~65)
#define NBK 256                             // bucket-pass blocks
#define BCHUNK ((TOT_E + NBK - 1) / NBK)    // 3321 edges/block
// C=128, H=2

typedef unsigned short us8 __attribute__((ext_vector_type(8)));
typedef short s16x8 __attribute__((ext_vector_type(8)));
typedef float f32x4 __attribute__((ext_vector_type(4)));

static __device__ __forceinline__ float lrelu(float v) { return v > 0.0f ? v : 0.2f * v; }

static __device__ __forceinline__ unsigned short f2bf(float f) {
    unsigned int u = __float_as_uint(f);
    unsigned int r = (u + 0x7FFF + ((u >> 16) & 1)) >> 16;  // RNE
    return (unsigned short)r;
}
static __device__ __forceinline__ float bf2f(unsigned short u) {
    return __uint_as_float(((unsigned int)u) << 16);
}

// ---------------- CSR build: single-pass bucket + LDS csr ----------------
// bucket_kernel: each block reads a chunk of edges once, histograms by node-partition
// (p = dst>>8) in LDS, reserves a dense run per partition with ONE global atomic, then
// scatter-writes packed (dst<<16|src) into fixed-capacity buckets. All bucket writes dense.
__global__ __launch_bounds__(256) void bucket_kernel(const int* __restrict__ ei,
                                                     int* __restrict__ gcur,
                                                     unsigned int* __restrict__ buckets) {
    __shared__ int hist[NP];
    __shared__ int runb[NP];
    __shared__ unsigned int pk[BCHUNK + 7];
    int tid = threadIdx.x;
    for (int t = tid; t < NP; t += 256) hist[t] = 0;
    __syncthreads();
    int lo = blockIdx.x * BCHUNK;
    int hi = lo + BCHUNK < TOT_E ? lo + BCHUNK : TOT_E;
    for (int base = lo; base < lo + BCHUNK; base += 256) {
        int i = base + tid;
        if (i < hi) {
            int s, d;
            if (i < N_EDGES) { s = ei[i]; d = ei[N_EDGES + i]; }
            else { s = d = i - N_EDGES; }
            pk[i - lo] = ((unsigned)d << 16) | (unsigned)s;
            atomicAdd(&hist[d >> 8], 1);
        }
    }
    __syncthreads();
    for (int t = tid; t < NP; t += 256) runb[t] = atomicAdd(&gcur[t], hist[t]);
    __syncthreads();
    for (int base = lo; base < lo + BCHUNK; base += 256) {
        int i = base + tid;
        if (i < hi) {
            unsigned v = pk[i - lo];
            int p = v >> 24;                       // dst>>8
            int slot = atomicAdd(&runb[p], 1);     // runb = running cursor in bucket
            if (slot < BCAP) buckets[(size_t)p * BCAP + slot] = v;
        }
    }
}

// csr_kernel: one block per partition. Bucket -> LDS, LDS degree histogram, LDS scan ->
// pbeg/pend, LDS scatter of src ids, sequential copy-out. Global writes all streaming.
__global__ __launch_bounds__(256) void csr_kernel(const int* __restrict__ gcur,
                                                  const unsigned int* __restrict__ buckets,
                                                  int* __restrict__ pbeg, int* __restrict__ pend,
                                                  unsigned short* __restrict__ srcs) {
    __shared__ unsigned int epk[BCAP];      // 24 KB
    __shared__ unsigned short sl[BCAP];     // 12 KB
    __shared__ int deg[256], ps[256], cur[256];
    int p = blockIdx.x, tid = threadIdx.x;
    int len = gcur[p];
    if (len > BCAP) len = BCAP;
    deg[tid] = 0;
    __syncthreads();
    for (int j = tid; j < len; j += 256) {
        unsigned v = buckets[(size_t)p * BCAP + j];
        epk[j] = v;
        atomicAdd(&deg[(v >> 16) & 255], 1);
    }
    __syncthreads();
    int v0 = deg[tid];
    ps[tid] = v0;
    __syncthreads();
#pragma unroll
    for (int o = 1; o < 256; o <<= 1) {
        int u = (tid >= o) ? ps[tid - o] : 0;
        __syncthreads();
        ps[tid] += u;
        __syncthreads();
    }
    int lbeg = ps[tid] - v0;
    cur[tid] = lbeg;
    int n = p * PS + tid;
    if (n < N_NODES) {
        pbeg[n] = p * BCAP + lbeg;
        pend[n] = p * BCAP + lbeg + v0;
    }
    __syncthreads();
    for (int j = tid; j < len; j += 256) {
        unsigned v = epk[j];
        int slot = atomicAdd(&cur[(v >> 16) & 255], 1);
        sl[slot] = (unsigned short)(v & 0xFFFF);
    }
    __syncthreads();
    for (int j = tid; j < len; j += 256) srcs[(size_t)p * BCAP + j] = sl[j];
}

// ---------------- precompute ----------------
__global__ __launch_bounds__(256) void convert_kernel(const float* __restrict__ x, unsigned short* __restrict__ xb) {
    int total = N_NODES * 32;
    for (int i = blockIdx.x * 256 + threadIdx.x; i < total; i += gridDim.x * 256) {
        float4 v = ((const float4*)x)[i];
        ushort4 o;
        o.x = f2bf(v.x); o.y = f2bf(v.y); o.z = f2bf(v.z); o.w = f2bf(v.w);
        ((ushort4*)xb)[i] = o;
    }
}

// wa_s[l][head][k] = sum_c W[l][k][head*128+c]*as[l][head][c]; same for wa_d. blockIdx = l.
__global__ __launch_bounds__(256) void wa_kernel(const float* __restrict__ W, const float* __restrict__ as_,
                                                 const float* __restrict__ ad_, float* __restrict__ was,
                                                 float* __restrict__ wad) {
    int l = blockIdx.x;
    int t = threadIdx.x;
    int head = t >> 7, k = t & 127;
    const float* wr = W + (size_t)l * 32768 + (size_t)k * 256 + head * 128;
    const float* ar = as_ + l * 256 + head * 128;
    const float* dr = ad_ + l * 256 + head * 128;
    float s = 0.f, d = 0.f;
    for (int c = 0; c < 128; ++c) {
        float wv = wr[c];
        s += wv * ar[c];
        d += wv * dr[c];
    }
    was[l * 256 + t] = s;
    wad[l * 256 + t] = d;
}

// Mt[l][c][kc] = bf16(0.5*W[l][kc&127][(kc>>7)*128 + c])  (B^T layout, 128 cols x 256 k)
__global__ __launch_bounds__(256) void mt_kernel(const float* __restrict__ W, unsigned short* __restrict__ Mt) {
    int idx = blockIdx.x * 256 + threadIdx.x;  // 65536
    int l = idx >> 15, c = (idx >> 8) & 127, kc = idx & 255;
    int head = kc >> 7, k = kc & 127;
    Mt[idx] = f2bf(0.5f * W[(size_t)l * 32768 + (size_t)k * 256 + head * 128 + c]);
}

// ---------------- per-layer kernels ----------------
// attention logits from fp32 x: als[n]={s_h0,s_h1}, ald[n]={d_h0,d_h1}. Wave per node, 2 cols/lane.
__global__ __launch_bounds__(256) void al_kernel(const float* __restrict__ x, const float* __restrict__ was,
                                                 const float* __restrict__ wad,
                                                 float2* __restrict__ als, float2* __restrict__ ald) {
    int n = (blockIdx.x * 256 + threadIdx.x) >> 6;
    int lane = threadIdx.x & 63;
    if (n >= N_NODES) return;
    float2 xv = *(const float2*)(x + (size_t)n * 128 + lane * 2);
    float2 ws0 = *(const float2*)(was + lane * 2);
    float2 ws1 = *(const float2*)(was + 128 + lane * 2);
    float2 wd0 = *(const float2*)(wad + lane * 2);
    float2 wd1 = *(const float2*)(wad + 128 + lane * 2);
    float s0 = xv.x * ws0.x + xv.y * ws0.y;
    float s1 = xv.x * ws1.x + xv.y * ws1.y;
    float d0 = xv.x * wd0.x + xv.y * wd0.y;
    float d1 = xv.x * wd1.x + xv.y * wd1.y;
#pragma unroll
    for (int o = 1; o < 64; o <<= 1) {
        s0 += __shfl_xor(s0, o);
        s1 += __shfl_xor(s1, o);
        d0 += __shfl_xor(d0, o);
        d1 += __shfl_xor(d1, o);
    }
    if (lane == 0) {
        als[n] = make_float2(s0, s1);
        ald[n] = make_float2(d0, d1);
    }
}

// 16-lane group per node (4 nodes/wave); lane covers 8 bf16 cols. Edges sequential per group,
// so exp/lrelu/denominator are lane-replicated (free in SIMD time) - no alpha precompute needed.
__global__ __launch_bounds__(256) void agg_kernel(const unsigned short* __restrict__ xb,
                                                  const float2* __restrict__ als, const float2* __restrict__ ald,
                                                  const int* __restrict__ pbeg, const int* __restrict__ pend,
                                                  const unsigned short* __restrict__ srcs,
                                                  unsigned short* __restrict__ y) {
    int tid = blockIdx.x * 256 + threadIdx.x;
    int n = tid >> 4;
    int gl = tid & 15;
    if (n >= N_NODES) return;
    int b = pbeg[n], e = pend[n];
    float2 ad = ald[n];
    int cb = gl * 8;   // col base

    float a0[8], a1[8];
#pragma unroll
    for (int j = 0; j < 8; ++j) { a0[j] = 0.f; a1[j] = 0.f; }
    float d0 = 0.f, d1 = 0.f;

    for (int i = b; i < e; ++i) {
        int s = srcs[i];
        float2 as2 = als[s];
        float w0 = __expf(lrelu(as2.x + ad.x));
        float w1 = __expf(lrelu(as2.y + ad.y));
        d0 += w0;
        d1 += w1;
        us8 v = *(const us8*)(xb + (size_t)s * 128 + cb);
#pragma unroll
        for (int j = 0; j < 8; ++j) {
            float f = bf2f(v[j]);
            a0[j] += w0 * f;
            a1[j] += w1 * f;
        }
    }

    float i0 = 1.0f / d0, i1 = 1.0f / d1;
    us8 o0, o1;
#pragma unroll
    for (int j = 0; j < 8; ++j) {
        o0[j] = f2bf(a0[j] * i0);
        o1[j] = f2bf(a1[j] * i1);
    }
    unsigned short* yp = y + (size_t)n * 256 + cb;
    *(us8*)yp = o0;
    *(us8*)(yp + 128) = o1;
}

// pre = z @ M + bias : (N,256)bf16 @ (256,128) -> fp32 (N,128). 4 waves x 16 rows.
__global__ __launch_bounds__(256) void gemm2_kernel(const unsigned short* __restrict__ zb,
                                                    const unsigned short* __restrict__ Mt,
                                                    const float* __restrict__ bias_,
                                                    float* __restrict__ pre) {
    __shared__ unsigned short lw[128 * 128];  // 32KB
    int t = threadIdx.x;
    int w = t >> 6, l = t & 63;
    int r0 = blockIdx.x * 64 + w * 16;
    int lrow = l & 15;
    int lk = l >> 4;

    int arow = r0 + lrow;
    if (arow >= N_NODES) arow = N_NODES - 1;

    f32x4 acc[8];
#pragma unroll
    for (int i = 0; i < 8; ++i) acc[i] = (f32x4){0.f, 0.f, 0.f, 0.f};

    for (int kh = 0; kh < 2; ++kh) {
#pragma unroll
        for (int i = 0; i < 8; ++i) {
            int chunk = t + i * 256;            // 0..2047
            int row = chunk >> 4;               // col 0..127
            int kc8 = chunk & 15;
            uint4 v = *(const uint4*)(Mt + (size_t)row * 256 + kh * 128 + kc8 * 8);
            int b = row * 256 + ((kc8 * 16) ^ ((row & 7) << 4));
            *(uint4*)((char*)lw + b) = v;
        }
        __syncthreads();
        s16x8 a[4];
#pragma unroll
        for (int ka = 0; ka < 4; ++ka)
            a[ka] = *(const s16x8*)(zb + (size_t)arow * 256 + kh * 128 + ka * 32 + lk * 8);
#pragma unroll
        for (int ct = 0; ct < 8; ++ct) {
            int row = ct * 16 + lrow;
#pragma unroll
            for (int ka = 0; ka < 4; ++ka) {
                int kb = (ka * 64 + lk * 16) ^ ((row & 7) << 4);
                s16x8 bf = *(const s16x8*)((const char*)lw + row * 256 + kb);
                acc[ct] = __builtin_amdgcn_mfma_f32_16x16x32_bf16(a[ka], bf, acc[ct], 0, 0, 0);
            }
        }
        __syncthreads();
    }

    // epilogue: transpose via LDS -> coalesced float4 stores (+bias)
    float* fl = (float*)lw;
    int wbase = w * 704;  // 4 rows x 176 words per wave
#pragma unroll
    for (int reg = 0; reg < 4; ++reg) {
#pragma unroll
        for (int ct = 0; ct < 8; ++ct)
            fl[wbase + lk * 176 + ct * 20 + lrow] = acc[ct][reg];
        __syncthreads();
        int lr2 = l >> 4;
        int cb2 = (l & 15) * 8;
        int ra = wbase + lr2 * 176 + (cb2 >> 4) * 20 + (cb2 & 15);
        f32x4 v0 = *(const f32x4*)(fl + ra);
        f32x4 v1 = *(const f32x4*)(fl + ra + 4);
        int row = r0 + lr2 * 4 + reg;
        if (row < N_NODES) {
            float4 b0 = *(const float4*)(bias_ + cb2);
            float4 b1 = *(const float4*)(bias_ + cb2 + 4);
            float4 o0 = make_float4(v0[0] + b0.x, v0[1] + b0.y, v0[2] + b0.z, v0[3] + b0.w);
            float4 o1 = make_float4(v1[0] + b1.x, v1[1] + b1.y, v1[2] + b1.z, v1[3] + b1.w);
            *(float4*)(pre + (size_t)row * 128 + cb2) = o0;
            *(float4*)(pre + (size_t)row * 128 + cb2 + 4) = o1;
        }
        __syncthreads();
    }
}

// per-channel sum and sumsq
__global__ __launch_bounds__(256) void stats_kernel(const float* __restrict__ pre, float* __restrict__ stats) {
    __shared__ float ls[256], lq[256];
    int t = threadIdx.x;
    int c = t & 127, half = t >> 7;
    float s = 0.f, q = 0.f;
    for (int r = blockIdx.x * 2 + half; r < N_NODES; r += gridDim.x * 2) {
        float v = pre[(size_t)r * 128 + c];
        s += v;
        q += v * v;
    }
    ls[t] = s;
    lq[t] = q;
    __syncthreads();
    if (half == 0) {
        atomicAdd(&stats[c], s + ls[128 + c]);
        atomicAdd(&stats[128 + c], q + lq[128 + c]);
    }
}

// BN + ELU + residual (+ optional bf16 copy for next layer's gather)
__global__ __launch_bounds__(256) void final_kernel(const float* __restrict__ pre, const float* __restrict__ res,
                                                    const float* __restrict__ gamma, const float* __restrict__ beta,
                                                    const float* __restrict__ stats, float* __restrict__ out,
                                                    unsigned short* __restrict__ xb_out) {
    const float invn = 1.0f / (float)N_NODES;
    int total = N_NODES * 32;
    for (int idx = blockIdx.x * 256 + threadIdx.x; idx < total; idx += gridDim.x * 256) {
        int c4 = (idx & 31) * 4;
        float4 v = ((const float4*)pre)[idx];
        float4 r = ((const float4*)res)[idx];
        const float* vp = (const float*)&v;
        const float* rp = (const float*)&r;
        float4 ov;
        float* op = (float*)&ov;
#pragma unroll
        for (int j = 0; j < 4; ++j) {
            int c = c4 + j;
            float mean = stats[c] * invn;
            float var = stats[128 + c] * invn - mean * mean;
            float is = rsqrtf(var + 1e-5f) * gamma[c];
            float val = (vp[j] - mean) * is + beta[c];
            val = val > 0.f ? val : (__expf(val) - 1.0f);
            op[j] = val + rp[j];
        }
        ((float4*)out)[idx] = ov;
        if (xb_out) {
            ushort4 ob;
            ob.x = f2bf(ov.x); ob.y = f2bf(ov.y); ob.z = f2bf(ov.z); ob.w = f2bf(ov.w);
            ((ushort4*)xb_out)[idx] = ob;
        }
    }
}

extern "C" void kernel_launch(void* const* d_in, const int* in_sizes, int n_in,
                              void* d_out, int out_size, void* d_ws, size_t ws_size,
                              hipStream_t stream) {
    const float* x0   = (const float*)d_in[0];
    const int* ei     = (const int*)d_in[1];
    const float* W    = (const float*)d_in[2];
    const float* asrc = (const float*)d_in[3];
    const float* adst = (const float*)d_in[4];
    const float* bias = (const float*)d_in[5];
    const float* gam  = (const float*)d_in[6];
    const float* bet  = (const float*)d_in[7];
    float* out = (float*)d_out;

    char* ws = (char*)d_ws;
    size_t off = 0;
    auto alloc = [&](size_t bytes) -> void* {
        void* p = ws + off;
        off += (bytes + 255) & ~(size_t)255;
        return p;
    };
    int* gcur   = (int*)alloc((size_t)NP * 4);
    unsigned int* buckets = (unsigned int*)alloc((size_t)NP * BCAP * 4);
    unsigned short* srcs  = (unsigned short*)alloc((size_t)NP * BCAP * 2);
    int* pbeg   = (int*)alloc((size_t)N_NODES * 4);
    int* pend   = (int*)alloc((size_t)N_NODES * 4);
    unsigned short* xb = (unsigned short*)alloc((size_t)N_NODES * 128 * 2);  // bf16 layer input (gather table)
    unsigned short* y  = (unsigned short*)alloc((size_t)N_NODES * 256 * 2);  // bf16 z = [y_h0|y_h1]
    unsigned short* Mt = (unsigned short*)alloc((size_t)2 * 128 * 256 * 2);  // bf16 M^T per layer
    float* was  = (float*)alloc(512 * 4);
    float* wad  = (float*)alloc(512 * 4);
    float* als  = (float*)alloc((size_t)N_NODES * 2 * 4);
    float* ald  = (float*)alloc((size_t)N_NODES * 2 * 4);
    float* pre  = (float*)alloc((size_t)N_NODES * 128 * 4);
    float* x1   = (float*)alloc((size_t)N_NODES * 128 * 4);
    float* stats = (float*)alloc(512 * 4);

    hipMemsetAsync(gcur, 0, (size_t)NP * 4, stream);
    hipMemsetAsync(stats, 0, 512 * 4, stream);

    bucket_kernel<<<NBK, 256, 0, stream>>>(ei, gcur, buckets);
    csr_kernel<<<NP, 256, 0, stream>>>(gcur, buckets, pbeg, pend, srcs);
    convert_kernel<<<2048, 256, 0, stream>>>(x0, xb);
    wa_kernel<<<2, 256, 0, stream>>>(W, asrc, adst, was, wad);
    mt_kernel<<<256, 256, 0, stream>>>(W, Mt);

    for (int l = 0; l < 2; ++l) {
        const float* xin = l ? (const float*)x1 : x0;
        float* xout = l ? out : x1;
        al_kernel<<<(N_NODES + 3) / 4, 256, 0, stream>>>(
            xin, was + l * 256, wad + l * 256, (float2*)als, (float2*)ald);
        agg_kernel<<<(N_NODES * 16 + 255) / 256, 256, 0, stream>>>(
            xb, (const float2*)als, (const float2*)ald, pbeg, pend, srcs, y);
        gemm2_kernel<<<(N_NODES + 63) / 64, 256, 0, stream>>>(
            y, Mt + (size_t)l * 32768, bias + l * 128, pre);
        stats_kernel<<<256, 256, 0, stream>>>(pre, stats + l * 256);
        final_kernel<<<2048, 256, 0, stream>>>(pre, xin, gam + l * 128, bet + l * 128, stats + l * 256,
                                               xout, l == 0 ? xb : (unsigned short*)nullptr);
    }
}

// Round 10
// 209.802 us; speedup vs baseline: 3.3745x; 1.3304x over previous
//
#include <hip/hip_runtime.h>
#include <hip/hip_bf16.h>

#define N_NODES 50000
#define N_EDGES 800000
#define TOT_E (N_EDGES + N_NODES)
#define PS 256                              // nodes per partition
#define NP ((N_NODES + PS - 1) / PS)        // 196 partitions
#define BCAP 6000                           // bucket capacity (avg 4352, sd ~65)
#define NBK 256                             // bucket-pass blocks
#define BCHUNK ((TOT_E + NBK - 1) / NBK)    // 3321 edges/block
// C=128, H=2

typedef unsigned short us8 __attribute__((ext_vector_type(8)));
typedef short s16x8 __attribute__((ext_vector_type(8)));
typedef float f32x4 __attribute__((ext_vector_type(4)));

static __device__ __forceinline__ float lrelu(float v) { return v > 0.0f ? v : 0.2f * v; }

static __device__ __forceinline__ unsigned short f2bf(float f) {
    unsigned int u = __float_as_uint(f);
    unsigned int r = (u + 0x7FFF + ((u >> 16) & 1)) >> 16;  // RNE
    return (unsigned short)r;
}
static __device__ __forceinline__ float bf2f(unsigned short u) {
    return __uint_as_float(((unsigned int)u) << 16);
}

// ---------------- CSR build: single-pass bucket + LDS csr ----------------
__global__ __launch_bounds__(256) void bucket_kernel(const int* __restrict__ ei,
                                                     int* __restrict__ gcur,
                                                     unsigned int* __restrict__ buckets) {
    __shared__ int hist[NP];
    __shared__ int runb[NP];
    __shared__ unsigned int pk[BCHUNK + 7];
    int tid = threadIdx.x;
    for (int t = tid; t < NP; t += 256) hist[t] = 0;
    __syncthreads();
    int lo = blockIdx.x * BCHUNK;
    int hi = lo + BCHUNK < TOT_E ? lo + BCHUNK : TOT_E;
    for (int base = lo; base < lo + BCHUNK; base += 256) {
        int i = base + tid;
        if (i < hi) {
            int s, d;
            if (i < N_EDGES) { s = ei[i]; d = ei[N_EDGES + i]; }
            else { s = d = i - N_EDGES; }
            pk[i - lo] = ((unsigned)d << 16) | (unsigned)s;
            atomicAdd(&hist[d >> 8], 1);
        }
    }
    __syncthreads();
    for (int t = tid; t < NP; t += 256) runb[t] = atomicAdd(&gcur[t], hist[t]);
    __syncthreads();
    for (int base = lo; base < lo + BCHUNK; base += 256) {
        int i = base + tid;
        if (i < hi) {
            unsigned v = pk[i - lo];
            int p = v >> 24;
            int slot = atomicAdd(&runb[p], 1);
            if (slot < BCAP) buckets[(size_t)p * BCAP + slot] = v;
        }
    }
}

__global__ __launch_bounds__(256) void csr_kernel(const int* __restrict__ gcur,
                                                  const unsigned int* __restrict__ buckets,
                                                  int* __restrict__ pbeg, int* __restrict__ pend,
                                                  unsigned short* __restrict__ srcs) {
    __shared__ unsigned int epk[BCAP];      // 24 KB
    __shared__ unsigned short sl[BCAP];     // 12 KB
    __shared__ int deg[256], ps[256], cur[256];
    int p = blockIdx.x, tid = threadIdx.x;
    int len = gcur[p];
    if (len > BCAP) len = BCAP;
    deg[tid] = 0;
    __syncthreads();
    for (int j = tid; j < len; j += 256) {
        unsigned v = buckets[(size_t)p * BCAP + j];
        epk[j] = v;
        atomicAdd(&deg[(v >> 16) & 255], 1);
    }
    __syncthreads();
    int v0 = deg[tid];
    ps[tid] = v0;
    __syncthreads();
#pragma unroll
    for (int o = 1; o < 256; o <<= 1) {
        int u = (tid >= o) ? ps[tid - o] : 0;
        __syncthreads();
        ps[tid] += u;
        __syncthreads();
    }
    int lbeg = ps[tid] - v0;
    cur[tid] = lbeg;
    int n = p * PS + tid;
    if (n < N_NODES) {
        pbeg[n] = p * BCAP + lbeg;
        pend[n] = p * BCAP + lbeg + v0;
    }
    __syncthreads();
    for (int j = tid; j < len; j += 256) {
        unsigned v = epk[j];
        int slot = atomicAdd(&cur[(v >> 16) & 255], 1);
        sl[slot] = (unsigned short)(v & 0xFFFF);
    }
    __syncthreads();
    for (int j = tid; j < len; j += 256) srcs[(size_t)p * BCAP + j] = sl[j];
}

// ---------------- precompute ----------------
// wa_s[l][head][k] = sum_c W[l][k][head*128+c]*as[l][head][c]; same for wa_d. blockIdx = l.
__global__ __launch_bounds__(256) void wa_kernel(const float* __restrict__ W, const float* __restrict__ as_,
                                                 const float* __restrict__ ad_, float* __restrict__ was,
                                                 float* __restrict__ wad) {
    int l = blockIdx.x;
    int t = threadIdx.x;
    int head = t >> 7, k = t & 127;
    const float* wr = W + (size_t)l * 32768 + (size_t)k * 256 + head * 128;
    const float* ar = as_ + l * 256 + head * 128;
    const float* dr = ad_ + l * 256 + head * 128;
    float s = 0.f, d = 0.f;
    for (int c = 0; c < 128; ++c) {
        float wv = wr[c];
        s += wv * ar[c];
        d += wv * dr[c];
    }
    was[l * 256 + t] = s;
    wad[l * 256 + t] = d;
}

// Mt[l][c][kc] = bf16(0.5*W[l][kc&127][(kc>>7)*128 + c])  (B^T layout, 128 cols x 256 k)
__global__ __launch_bounds__(256) void mt_kernel(const float* __restrict__ W, unsigned short* __restrict__ Mt) {
    int idx = blockIdx.x * 256 + threadIdx.x;  // 65536
    int l = idx >> 15, c = (idx >> 8) & 127, kc = idx & 255;
    int head = kc >> 7, k = kc & 127;
    Mt[idx] = f2bf(0.5f * W[(size_t)l * 32768 + (size_t)k * 256 + head * 128 + c]);
}

// x (fp32) -> xb (bf16) + layer-0 attention logits (32 threads per node, shuffle reduce).
// grid exact: N_NODES*32/256 = 6250 blocks.
__global__ __launch_bounds__(256) void convert_kernel(const float* __restrict__ x, unsigned short* __restrict__ xb,
                                                      const float* __restrict__ was, const float* __restrict__ wad,
                                                      float2* __restrict__ als, float2* __restrict__ ald) {
    int idx = blockIdx.x * 256 + threadIdx.x;
    int n = idx >> 5;
    int c4 = (idx & 31) * 4;
    float4 v = *(const float4*)(x + (size_t)n * 128 + c4);
    ushort4 o;
    o.x = f2bf(v.x); o.y = f2bf(v.y); o.z = f2bf(v.z); o.w = f2bf(v.w);
    *(ushort4*)(xb + (size_t)n * 128 + c4) = o;
    float4 ws0 = *(const float4*)(was + c4);
    float4 ws1 = *(const float4*)(was + 128 + c4);
    float4 wd0 = *(const float4*)(wad + c4);
    float4 wd1 = *(const float4*)(wad + 128 + c4);
    float s0 = v.x * ws0.x + v.y * ws0.y + v.z * ws0.z + v.w * ws0.w;
    float s1 = v.x * ws1.x + v.y * ws1.y + v.z * ws1.z + v.w * ws1.w;
    float d0 = v.x * wd0.x + v.y * wd0.y + v.z * wd0.z + v.w * wd0.w;
    float d1 = v.x * wd1.x + v.y * wd1.y + v.z * wd1.z + v.w * wd1.w;
#pragma unroll
    for (int o2 = 1; o2 < 32; o2 <<= 1) {
        s0 += __shfl_xor(s0, o2);
        s1 += __shfl_xor(s1, o2);
        d0 += __shfl_xor(d0, o2);
        d1 += __shfl_xor(d1, o2);
    }
    if ((idx & 31) == 0) {
        als[n] = make_float2(s0, s1);
        ald[n] = make_float2(d0, d1);
    }
}

// ---------------- per-layer kernels ----------------
// 16-lane group per node (4 nodes/wave); lane covers 8 bf16 cols. TWO independent edge
// streams per group (ILP x2): 2 row-gathers + 2 als in flight per group, 8 per wave.
__global__ __launch_bounds__(256) void agg_kernel(const unsigned short* __restrict__ xb,
                                                  const float2* __restrict__ als, const float2* __restrict__ ald,
                                                  const int* __restrict__ pbeg, const int* __restrict__ pend,
                                                  const unsigned short* __restrict__ srcs,
                                                  unsigned short* __restrict__ y) {
    int tid = blockIdx.x * 256 + threadIdx.x;
    int n = tid >> 4;
    int gl = tid & 15;
    if (n >= N_NODES) return;
    int b = pbeg[n], e = pend[n];
    float2 ad = ald[n];
    int cb = gl * 8;   // col base

    float a0[8], a1[8];
#pragma unroll
    for (int j = 0; j < 8; ++j) { a0[j] = 0.f; a1[j] = 0.f; }
    float d0 = 0.f, d1 = 0.f;

    int len = e - b;
    int m = len >> 1;        // stream A count
    int b2 = b + m;          // stream B start
    int lenB = len - m;      // >= m >= 0 (len >= 1: self-loop)
    for (int i = 0; i < lenB; ++i) {
        bool actA = i < m;
        int iA = actA ? (b + i) : (b2 + i);
        int sA = srcs[iA];
        int sB = srcs[b2 + i];
        float2 asA = als[sA];
        float2 asB = als[sB];
        us8 vA = *(const us8*)(xb + (size_t)sA * 128 + cb);
        us8 vB = *(const us8*)(xb + (size_t)sB * 128 + cb);
        float w0A = actA ? __expf(lrelu(asA.x + ad.x)) : 0.f;
        float w1A = actA ? __expf(lrelu(asA.y + ad.y)) : 0.f;
        float w0B = __expf(lrelu(asB.x + ad.x));
        float w1B = __expf(lrelu(asB.y + ad.y));
        d0 += w0A + w0B;
        d1 += w1A + w1B;
#pragma unroll
        for (int j = 0; j < 8; ++j) {
            float fA = bf2f(vA[j]);
            float fB = bf2f(vB[j]);
            a0[j] += w0A * fA + w0B * fB;
            a1[j] += w1A * fA + w1B * fB;
        }
    }

    float i0 = 1.0f / d0, i1 = 1.0f / d1;
    us8 o0, o1;
#pragma unroll
    for (int j = 0; j < 8; ++j) {
        o0[j] = f2bf(a0[j] * i0);
        o1[j] = f2bf(a1[j] * i1);
    }
    unsigned short* yp = y + (size_t)n * 256 + cb;
    *(us8*)yp = o0;
    *(us8*)(yp + 128) = o1;
}

// pre = z @ M + bias : (N,256)bf16 @ (256,128) -> bf16 (N,128) + fused BN stats.
__global__ __launch_bounds__(256) void gemm2_kernel(const unsigned short* __restrict__ zb,
                                                    const unsigned short* __restrict__ Mt,
                                                    const float* __restrict__ bias_,
                                                    unsigned short* __restrict__ preb,
                                                    float* __restrict__ stats) {
    __shared__ unsigned short lw[128 * 128];  // 32KB
    __shared__ float redsum[4][128];
    __shared__ float redsq[4][128];
    int t = threadIdx.x;
    int w = t >> 6, l = t & 63;
    int r0 = blockIdx.x * 64 + w * 16;
    int lrow = l & 15;
    int lk = l >> 4;

    int arow = r0 + lrow;
    if (arow >= N_NODES) arow = N_NODES - 1;

    f32x4 acc[8];
#pragma unroll
    for (int i = 0; i < 8; ++i) acc[i] = (f32x4){0.f, 0.f, 0.f, 0.f};

    for (int kh = 0; kh < 2; ++kh) {
#pragma unroll
        for (int i = 0; i < 8; ++i) {
            int chunk = t + i * 256;            // 0..2047
            int row = chunk >> 4;               // col 0..127
            int kc8 = chunk & 15;
            uint4 v = *(const uint4*)(Mt + (size_t)row * 256 + kh * 128 + kc8 * 8);
            int b = row * 256 + ((kc8 * 16) ^ ((row & 7) << 4));
            *(uint4*)((char*)lw + b) = v;
        }
        __syncthreads();
        s16x8 a[4];
#pragma unroll
        for (int ka = 0; ka < 4; ++ka)
            a[ka] = *(const s16x8*)(zb + (size_t)arow * 256 + kh * 128 + ka * 32 + lk * 8);
#pragma unroll
        for (int ct = 0; ct < 8; ++ct) {
            int row = ct * 16 + lrow;
#pragma unroll
            for (int ka = 0; ka < 4; ++ka) {
                int kb = (ka * 64 + lk * 16) ^ ((row & 7) << 4);
                s16x8 bf = *(const s16x8*)((const char*)lw + row * 256 + kb);
                acc[ct] = __builtin_amdgcn_mfma_f32_16x16x32_bf16(a[ka], bf, acc[ct], 0, 0, 0);
            }
        }
        __syncthreads();
    }

    // epilogue: LDS transpose -> bf16 stores + per-thread stats accumulation
    float* fl = (float*)lw;
    int wbase = w * 704;  // 4 rows x 176 words per wave
    int lr2 = l >> 4;
    int cb2 = (l & 15) * 8;
    float4 b0 = *(const float4*)(bias_ + cb2);
    float4 b1 = *(const float4*)(bias_ + cb2 + 4);
    float ssum[8], ssq[8];
#pragma unroll
    for (int j = 0; j < 8; ++j) { ssum[j] = 0.f; ssq[j] = 0.f; }
#pragma unroll
    for (int reg = 0; reg < 4; ++reg) {
#pragma unroll
        for (int ct = 0; ct < 8; ++ct)
            fl[wbase + lk * 176 + ct * 20 + lrow] = acc[ct][reg];
        __syncthreads();
        int ra = wbase + lr2 * 176 + (cb2 >> 4) * 20 + (cb2 & 15);
        f32x4 v0 = *(const f32x4*)(fl + ra);
        f32x4 v1 = *(const f32x4*)(fl + ra + 4);
        int row = r0 + lr2 * 4 + reg;
        if (row < N_NODES) {
            float vals[8] = {v0[0] + b0.x, v0[1] + b0.y, v0[2] + b0.z, v0[3] + b0.w,
                             v1[0] + b1.x, v1[1] + b1.y, v1[2] + b1.z, v1[3] + b1.w};
            us8 ob;
#pragma unroll
            for (int j = 0; j < 8; ++j) {
                ob[j] = f2bf(vals[j]);
                ssum[j] += vals[j];
                ssq[j] += vals[j] * vals[j];
            }
            *(us8*)(preb + (size_t)row * 128 + cb2) = ob;
        }
        __syncthreads();
    }
    // stats: reduce the 4 lanes sharing cb2 (xor 16, 32), stash per wave, reduce waves, atomics
#pragma unroll
    for (int j = 0; j < 8; ++j) {
        ssum[j] += __shfl_xor(ssum[j], 16);
        ssum[j] += __shfl_xor(ssum[j], 32);
        ssq[j] += __shfl_xor(ssq[j], 16);
        ssq[j] += __shfl_xor(ssq[j], 32);
    }
    if (l < 16) {
#pragma unroll
        for (int j = 0; j < 8; ++j) {
            redsum[w][cb2 + j] = ssum[j];
            redsq[w][cb2 + j] = ssq[j];
        }
    }
    __syncthreads();
    if (t < 128) {
        atomicAdd(&stats[t], redsum[0][t] + redsum[1][t] + redsum[2][t] + redsum[3][t]);
    } else if (t < 256) {
        int c = t - 128;
        atomicAdd(&stats[128 + c], redsq[0][c] + redsq[1][c] + redsq[2][c] + redsq[3][c]);
    }
}

// BN + ELU + residual from bf16 pre; optionally emits bf16 x_{l+1} and next-layer logits.
// grid exact: N_NODES*16/256 = 3125 blocks. 16 threads per node.
__global__ __launch_bounds__(256) void final_kernel(const unsigned short* __restrict__ preb,
                                                    const float* __restrict__ res,
                                                    const float* __restrict__ gamma, const float* __restrict__ beta,
                                                    const float* __restrict__ stats, float* __restrict__ out,
                                                    unsigned short* __restrict__ xb_out,
                                                    const float* __restrict__ was_n, const float* __restrict__ wad_n,
                                                    float2* __restrict__ als_o, float2* __restrict__ ald_o) {
    const float invn = 1.0f / (float)N_NODES;
    int idx = blockIdx.x * 256 + threadIdx.x;
    int n = idx >> 4;
    int c8 = (idx & 15) * 8;
    us8 pv = *(const us8*)(preb + (size_t)n * 128 + c8);
    float4 r0 = *(const float4*)(res + (size_t)n * 128 + c8);
    float4 r1 = *(const float4*)(res + (size_t)n * 128 + c8 + 4);
    float4 sm0 = *(const float4*)(stats + c8);
    float4 sm1 = *(const float4*)(stats + c8 + 4);
    float4 sq0 = *(const float4*)(stats + 128 + c8);
    float4 sq1 = *(const float4*)(stats + 128 + c8 + 4);
    float4 g0 = *(const float4*)(gamma + c8);
    float4 g1 = *(const float4*)(gamma + c8 + 4);
    float4 bt0 = *(const float4*)(beta + c8);
    float4 bt1 = *(const float4*)(beta + c8 + 4);
    float sm[8] = {sm0.x, sm0.y, sm0.z, sm0.w, sm1.x, sm1.y, sm1.z, sm1.w};
    float sq[8] = {sq0.x, sq0.y, sq0.z, sq0.w, sq1.x, sq1.y, sq1.z, sq1.w};
    float gg[8] = {g0.x, g0.y, g0.z, g0.w, g1.x, g1.y, g1.z, g1.w};
    float bb[8] = {bt0.x, bt0.y, bt0.z, bt0.w, bt1.x, bt1.y, bt1.z, bt1.w};
    float rs[8] = {r0.x, r0.y, r0.z, r0.w, r1.x, r1.y, r1.z, r1.w};
    float vals[8];
#pragma unroll
    for (int j = 0; j < 8; ++j) {
        float mean = sm[j] * invn;
        float var = sq[j] * invn - mean * mean;
        float is = rsqrtf(var + 1e-5f) * gg[j];
        float val = (bf2f(pv[j]) - mean) * is + bb[j];
        val = val > 0.f ? val : (__expf(val) - 1.0f);
        vals[j] = val + rs[j];
    }
    float* op = out + (size_t)n * 128 + c8;
    *(float4*)op = make_float4(vals[0], vals[1], vals[2], vals[3]);
    *(float4*)(op + 4) = make_float4(vals[4], vals[5], vals[6], vals[7]);
    if (xb_out) {
        us8 ob;
#pragma unroll
        for (int j = 0; j < 8; ++j) ob[j] = f2bf(vals[j]);
        *(us8*)(xb_out + (size_t)n * 128 + c8) = ob;
        // next-layer attention logits
        float s0 = 0.f, s1 = 0.f, d0 = 0.f, d1 = 0.f;
#pragma unroll
        for (int j = 0; j < 8; ++j) {
            int c = c8 + j;
            s0 += vals[j] * was_n[c];
            s1 += vals[j] * was_n[128 + c];
            d0 += vals[j] * wad_n[c];
            d1 += vals[j] * wad_n[128 + c];
        }
#pragma unroll
        for (int o = 1; o < 16; o <<= 1) {
            s0 += __shfl_xor(s0, o);
            s1 += __shfl_xor(s1, o);
            d0 += __shfl_xor(d0, o);
            d1 += __shfl_xor(d1, o);
        }
        if ((idx & 15) == 0) {
            als_o[n] = make_float2(s0, s1);
            ald_o[n] = make_float2(d0, d1);
        }
    }
}

extern "C" void kernel_launch(void* const* d_in, const int* in_sizes, int n_in,
                              void* d_out, int out_size, void* d_ws, size_t ws_size,
                              hipStream_t stream) {
    const float* x0   = (const float*)d_in[0];
    const int* ei     = (const int*)d_in[1];
    const float* W    = (const float*)d_in[2];
    const float* asrc = (const float*)d_in[3];
    const float* adst = (const float*)d_in[4];
    const float* bias = (const float*)d_in[5];
    const float* gam  = (const float*)d_in[6];
    const float* bet  = (const float*)d_in[7];
    float* out = (float*)d_out;

    char* ws = (char*)d_ws;
    size_t off = 0;
    auto alloc = [&](size_t bytes) -> void* {
        void* p = ws + off;
        off += (bytes + 255) & ~(size_t)255;
        return p;
    };
    int* gcur   = (int*)alloc((size_t)NP * 4);
    unsigned int* buckets = (unsigned int*)alloc((size_t)NP * BCAP * 4);
    unsigned short* srcs  = (unsigned short*)alloc((size_t)NP * BCAP * 2);
    int* pbeg   = (int*)alloc((size_t)N_NODES * 4);
    int* pend   = (int*)alloc((size_t)N_NODES * 4);
    unsigned short* xb = (unsigned short*)alloc((size_t)N_NODES * 128 * 2);   // bf16 layer input
    unsigned short* y  = (unsigned short*)alloc((size_t)N_NODES * 256 * 2);   // bf16 z = [y_h0|y_h1]
    unsigned short* preb = (unsigned short*)alloc((size_t)N_NODES * 128 * 2); // bf16 pre-BN
    unsigned short* Mt = (unsigned short*)alloc((size_t)2 * 128 * 256 * 2);   // bf16 M^T per layer
    float* was  = (float*)alloc(512 * 4);
    float* wad  = (float*)alloc(512 * 4);
    float* als  = (float*)alloc((size_t)N_NODES * 2 * 4);
    float* ald  = (float*)alloc((size_t)N_NODES * 2 * 4);
    float* x1   = (float*)alloc((size_t)N_NODES * 128 * 4);
    float* stats = (float*)alloc(512 * 4);

    hipMemsetAsync(gcur, 0, (size_t)NP * 4, stream);
    hipMemsetAsync(stats, 0, 512 * 4, stream);

    bucket_kernel<<<NBK, 256, 0, stream>>>(ei, gcur, buckets);
    csr_kernel<<<NP, 256, 0, stream>>>(gcur, buckets, pbeg, pend, srcs);
    wa_kernel<<<2, 256, 0, stream>>>(W, asrc, adst, was, wad);
    mt_kernel<<<256, 256, 0, stream>>>(W, Mt);
    convert_kernel<<<(N_NODES * 32) / 256, 256, 0, stream>>>(x0, xb, was, wad, (float2*)als, (float2*)ald);

    for (int l = 0; l < 2; ++l) {
        const float* xin = l ? (const float*)x1 : x0;
        float* xout = l ? out : x1;
        agg_kernel<<<(N_NODES * 16 + 255) / 256, 256, 0, stream>>>(
            xb, (const float2*)als, (const float2*)ald, pbeg, pend, srcs, y);
        gemm2_kernel<<<(N_NODES + 63) / 64, 256, 0, stream>>>(
            y, Mt + (size_t)l * 32768, bias + l * 128, preb, stats + l * 256);
        final_kernel<<<(N_NODES * 16) / 256, 256, 0, stream>>>(
            preb, xin, gam + l * 128, bet + l * 128, stats + l * 256, xout,
            l == 0 ? xb : (unsigned short*)nullptr, was + 256, wad + 256,
            (float2*)als, (float2*)ald);
    }
}